// Round 15
// baseline (442.087 us; speedup 1.0000x reference)
//
#include <hip/hip_runtime.h>

static constexpr float BN_EPS = 1e-5f;
typedef unsigned int uint;
typedef unsigned short ushort;
typedef __attribute__((ext_vector_type(8))) short bf16x8;
typedef __attribute__((ext_vector_type(4))) float f32x4;

__device__ __forceinline__ void fatomic_add(float* p, float v) {
  unsafeAtomicAdd(p, v);  // HW global_atomic_add_f32
}

__device__ __forceinline__ ushort f2bf(float f) {  // f32 -> bf16 RNE
  uint u = __float_as_uint(f);
  u += 0x7fffu + ((u >> 16) & 1u);
  return (ushort)(u >> 16);
}

__device__ __forceinline__ float4 bf4_decode(uint2 r) {
  return make_float4(__uint_as_float(r.x << 16), __uint_as_float(r.x & 0xffff0000u),
                     __uint_as_float(r.y << 16), __uint_as_float(r.y & 0xffff0000u));
}

// histogram keyed by col; stores each edge's arrival rank (for atomic-free fill)
__global__ void k_hist(const int* __restrict__ col, int* __restrict__ cnt,
                       int* __restrict__ rank, int e) {
  int i = blockIdx.x * 256 + threadIdx.x;
  if (i < e) rank[i] = atomicAdd(&cnt[col[i]], 1);
}

// ---- device-wide exclusive scan of cnt[n] (1024 elems/block) ----
__global__ __launch_bounds__(256) void k_scan_part(const int* __restrict__ cnt,
                                                   int* __restrict__ bsum, int n) {
  __shared__ int sm[256];
  int t = threadIdx.x;
  int base = blockIdx.x * 1024 + t * 4;
  int s = 0;
#pragma unroll
  for (int j = 0; j < 4; j++) {
    int i = base + j;
    if (i < n) s += cnt[i];
  }
  sm[t] = s;
  __syncthreads();
  for (int off = 128; off > 0; off >>= 1) {
    if (t < off) sm[t] += sm[t + off];
    __syncthreads();
  }
  if (t == 0) bsum[blockIdx.x] = sm[0];
}

__global__ __launch_bounds__(1024) void k_scan_mid(int* __restrict__ bsum, int nb) {
  __shared__ int sm[1024];
  int t = threadIdx.x;
  int v = (t < nb) ? bsum[t] : 0;
  sm[t] = v;
  __syncthreads();
  for (int off = 1; off < 1024; off <<= 1) {
    int o = (t >= off) ? sm[t - off] : 0;
    __syncthreads();
    sm[t] += o;
    __syncthreads();
  }
  if (t < nb) bsum[t] = sm[t] - v;  // exclusive block offsets
}

__global__ __launch_bounds__(256) void k_scan_apply(const int* __restrict__ cnt,
                                                    int* __restrict__ ptr,
                                                    const int* __restrict__ bsum,
                                                    int n, int e) {
  __shared__ int sm[256];
  int t = threadIdx.x;
  int base = blockIdx.x * 1024 + t * 4;
  int v[4];
  int s = 0;
#pragma unroll
  for (int j = 0; j < 4; j++) {
    int i = base + j;
    v[j] = (i < n) ? cnt[i] : 0;
    s += v[j];
  }
  sm[t] = s;
  __syncthreads();
  for (int off = 1; off < 256; off <<= 1) {
    int o = (t >= off) ? sm[t - off] : 0;
    __syncthreads();
    sm[t] += o;
    __syncthreads();
  }
  int run = bsum[blockIdx.x] + sm[t] - s;
#pragma unroll
  for (int j = 0; j < 4; j++) {
    int i = base + j;
    if (i < n) {
      ptr[i] = run;
      run += v[j];
    }
  }
  if (blockIdx.x == 0 && t == 0) ptr[n] = e;
}

// atomic-free CSR fill: slot = ptr[col] + rank
__global__ void k_fillcsr(const int* __restrict__ row, const int* __restrict__ col,
                          const float* __restrict__ ew, const int* __restrict__ ptr,
                          const int* __restrict__ rank, int2* __restrict__ spair, int e) {
  int i = blockIdx.x * 256 + threadIdx.x;
  if (i >= e) return;
  int p = ptr[col[i]] + rank[i];
  spair[p] = make_int2(row[i], __float_as_int(ew[i]));
}

// per-node: deg = 1 (self-loop) + segment-sum of ew; dis = rsqrt(deg). No atomics.
__global__ void k_degdis(const int* __restrict__ ptr, const int2* __restrict__ spair,
                         float* __restrict__ dis, int n) {
  int v = blockIdx.x * 256 + threadIdx.x;
  if (v >= n) return;
  int b = ptr[v], en = ptr[v + 1];
  float s = 1.0f;
  for (int j = b; j < en; j++) s += __int_as_float(spair[j].y);
  dis[v] = rsqrtf(s);
}

// fold dis[row] into stored edge weight (dis[col] applied in k_agg)
__global__ void k_scale(int2* __restrict__ spair, const float* __restrict__ dis, int e) {
  int i = blockIdx.x * 256 + threadIdx.x;
  if (i >= e) return;
  int2 m = spair[i];
  spair[i] = make_int2(m.x, __float_as_int(__int_as_float(m.y) * dis[m.x]));
}

// ---- aggregation v5 + fused BN stats (structure unchanged from R14).
// Each 16-lane group owns a CONTIGUOUS node range; edges stream through a
// depth-3 chunk pipeline with node boundaries handled in the compute stage.
__global__ __launch_bounds__(256) void k_agg(
    const int* __restrict__ ptr, const int2* __restrict__ spair,
    const float* __restrict__ dis, const ushort* __restrict__ hwb,
    float* __restrict__ agg, float* __restrict__ stats, int n, int npg) {
  int tid = threadIdx.x;
  int lane = tid & 63;
  int li = lane & 15;
  int gbase = lane & 48;  // group base lane within wave (0,16,32,48)
  int gidx = (blockIdx.x * 256 + tid) >> 4;  // global group id
  float st_s[4] = {0.f, 0.f, 0.f, 0.f};
  float st_q[4] = {0.f, 0.f, 0.f, 0.f};

  int v0 = gidx * npg;
  if (v0 < n) {
    int v1 = min(v0 + npg, n);
    int tmax = v1 - v0;  // <= npg <= 15
    // lane-parallel ptr/dis for the range
    int pv = ptr[min(v0 + li, n)];
    float dvr = dis[min(v0 + li, n - 1)];
    int begR = __shfl(pv, gbase);
    int jend = __shfl(pv, gbase + tmax);

    // node-walk state
    int v = v0, t = 0;
    float d = __shfl(dvr, gbase);
    int e_cur = __shfl(pv, gbase + 1);
    uint2 self_cur = *(const uint2*)(hwb + (size_t)v0 * 64 + li * 4);
    uint2 self_nxt = *(const uint2*)(hwb + (size_t)min(v0 + 1, n - 1) * 64 + li * 4);
    int vself = v0 + 2;
    float4 acc = make_float4(0.f, 0.f, 0.f, 0.f);

#define FINALIZE_NODE()                                                        \
  {                                                                            \
    float4 sf = bf4_decode(self_cur);                                          \
    float4 o;                                                                  \
    o.x = d * fmaf(d, sf.x, acc.x);                                            \
    o.y = d * fmaf(d, sf.y, acc.y);                                            \
    o.z = d * fmaf(d, sf.z, acc.z);                                            \
    o.w = d * fmaf(d, sf.w, acc.w);                                            \
    *(float4*)(agg + (size_t)v * 64 + li * 4) = o;                             \
    st_s[0] += o.x; st_s[1] += o.y; st_s[2] += o.z; st_s[3] += o.w;            \
    st_q[0] = fmaf(o.x, o.x, st_q[0]);                                         \
    st_q[1] = fmaf(o.y, o.y, st_q[1]);                                         \
    st_q[2] = fmaf(o.z, o.z, st_q[2]);                                         \
    st_q[3] = fmaf(o.w, o.w, st_q[3]);                                         \
    acc = make_float4(0.f, 0.f, 0.f, 0.f);                                     \
    self_cur = self_nxt;                                                       \
    self_nxt = *(const uint2*)(hwb + (size_t)min(vself, n - 1) * 64 + li * 4); \
    vself++;                                                                   \
    v++; t++;                                                                  \
    d = __shfl(dvr, gbase + min(t, 15));                                       \
    e_cur = __shfl(pv, gbase + min(t + 1, 15));                                \
  }

    if (begR < jend) {
      const int4* sp = (const int4*)spair;
      int jc = begR & ~3;
      int h = jc >> 1;
      int nch = (jend - jc + 3) >> 2;

      float wA[4], wB[4], wC_[4];
      uint2 gA[4], gB[4], gC_[4];
      int4 mN0, mN1;

      {  // prologue chunk 0
        int4 p0 = sp[h], p1 = sp[h + 1];
        int rr[4] = {p0.x, p0.z, p1.x, p1.z};
        int wi[4] = {p0.y, p0.w, p1.y, p1.w};
#pragma unroll
        for (int k = 0; k < 4; k++) {
          int j = jc + k;
          bool okk = (j >= begR) && (j < jend);
          int r = okk ? rr[k] : v0;
          wA[k] = okk ? __int_as_float(wi[k]) : 0.f;
          gA[k] = *(const uint2*)(hwb + (size_t)r * 64 + li * 4);
        }
      }
      if (nch > 1) {  // chunk 1
        int4 p0 = sp[h + 2], p1 = sp[h + 3];
        int rr[4] = {p0.x, p0.z, p1.x, p1.z};
        int wi[4] = {p0.y, p0.w, p1.y, p1.w};
#pragma unroll
        for (int k = 0; k < 4; k++) {
          bool okk = (jc + 4 + k) < jend;
          int r = okk ? rr[k] : v0;
          wB[k] = okk ? __int_as_float(wi[k]) : 0.f;
          gB[k] = *(const uint2*)(hwb + (size_t)r * 64 + li * 4);
        }
      }
      if (nch > 2) {  // chunk 2
        int4 p0 = sp[h + 4], p1 = sp[h + 5];
        int rr[4] = {p0.x, p0.z, p1.x, p1.z};
        int wi[4] = {p0.y, p0.w, p1.y, p1.w};
#pragma unroll
        for (int k = 0; k < 4; k++) {
          bool okk = (jc + 8 + k) < jend;
          int r = okk ? rr[k] : v0;
          wC_[k] = okk ? __int_as_float(wi[k]) : 0.f;
          gC_[k] = *(const uint2*)(hwb + (size_t)r * 64 + li * 4);
        }
      }
      if (nch > 3) { mN0 = sp[h + 6]; mN1 = sp[h + 7]; }

      for (int c = 0; c < nch; c++) {
        float wD[4];
        uint2 gD[4];
        if (c + 3 < nch) {  // issue gathers for chunk c+3
          int jn = jc + 12;
          int rr[4] = {mN0.x, mN0.z, mN1.x, mN1.z};
          int wi[4] = {mN0.y, mN0.w, mN1.y, mN1.w};
#pragma unroll
          for (int k = 0; k < 4; k++) {
            bool okk = (jn + k) < jend;
            int r = okk ? rr[k] : v0;
            wD[k] = okk ? __int_as_float(wi[k]) : 0.f;
            gD[k] = *(const uint2*)(hwb + (size_t)r * 64 + li * 4);
          }
        }
        if (c + 4 < nch) {  // prefetch meta for chunk c+4
          mN0 = sp[h + 2 * (c + 4)];
          mN1 = sp[h + 2 * (c + 4) + 1];
        }
        // compute chunk c with node-boundary advance
#pragma unroll
        for (int k = 0; k < 4; k++) {
          int j = jc + k;
          while (j >= e_cur && v < v1) FINALIZE_NODE();
          float4 f = bf4_decode(gA[k]);
          acc.x = fmaf(wA[k], f.x, acc.x);
          acc.y = fmaf(wA[k], f.y, acc.y);
          acc.z = fmaf(wA[k], f.z, acc.z);
          acc.w = fmaf(wA[k], f.w, acc.w);
        }
#pragma unroll
        for (int k = 0; k < 4; k++) {
          gA[k] = gB[k]; wA[k] = wB[k];
          gB[k] = gC_[k]; wB[k] = wC_[k];
        }
        if (c + 3 < nch) {
#pragma unroll
          for (int k = 0; k < 4; k++) { gC_[k] = gD[k]; wC_[k] = wD[k]; }
        }
        jc += 4;
      }
    }
    // epilogue: finalize remaining nodes (incl. zero-degree / tail)
    while (v < v1) FINALIZE_NODE();
#undef FINALIZE_NODE
  }

  // cross-group + block stats reduction
#pragma unroll
  for (int j = 0; j < 4; j++) {
    st_s[j] += __shfl_xor(st_s[j], 16);
    st_s[j] += __shfl_xor(st_s[j], 32);
    st_q[j] += __shfl_xor(st_q[j], 16);
    st_q[j] += __shfl_xor(st_q[j], 32);
  }
  __shared__ float rs[4][64];
  __shared__ float rq[4][64];
  int wv = tid >> 6;
  if (gbase == 0) {
#pragma unroll
    for (int j = 0; j < 4; j++) {
      rs[wv][li * 4 + j] = st_s[j];
      rq[wv][li * 4 + j] = st_q[j];
    }
  }
  __syncthreads();
  if (tid < 64) {
    int c = tid;
    float s = rs[0][c] + rs[1][c] + rs[2][c] + rs[3][c];
    float q = rq[0][c] + rq[1][c] + rq[2][c] + rq[3][c];
    fatomic_add(&stats[c], s);
    fatomic_add(&stats[64 + c], q);
  }
}

// ---- GEMM1 via MFMA: [n,128] @ [128,128]. (unchanged)
__global__ __launch_bounds__(256) void k_gemm1m(
    const float* __restrict__ x, const float* __restrict__ W1,
    const float* __restrict__ pW, const float* __restrict__ pb,
    ushort* __restrict__ ob, float* __restrict__ of, int n) {
  __shared__ ushort wT[128 * 128];  // 32 KB
  int tid = threadIdx.x;
  for (int idx = tid; idx < 128 * 64; idx += 256) {
    int c = idx >> 6;
    int kp = idx & 63;
    const float* src = (c < 64) ? (W1 + c) : (pW + (c - 64));
    float f0 = src[(size_t)(2 * kp) * 64];
    float f1 = src[(size_t)(2 * kp + 1) * 64];
    uint pk = (uint)f2bf(f0) | ((uint)f2bf(f1) << 16);
    int byte = c * 256 + kp * 4;
    byte ^= ((c & 7) << 4);
    *(uint*)((char*)wT + byte) = pk;
  }
  __syncthreads();

  int lane = tid & 63;
  int wv = tid >> 6;
  int lr = lane & 15;
  int lk = lane >> 4;
  int rowBase = blockIdx.x * 128 + wv * 32;

  f32x4 acc[2][8];
#pragma unroll
  for (int i = 0; i < 2; i++)
#pragma unroll
    for (int j = 0; j < 8; j++) acc[i][j] = (f32x4){0.f, 0.f, 0.f, 0.f};

  int r0 = rowBase + lr;
  int r1 = rowBase + 16 + lr;
  bool ok0 = r0 < n, ok1 = r1 < n;
  int swz = (lr & 7) << 4;

#pragma unroll
  for (int ks = 0; ks < 4; ks++) {
    int k0 = ks * 32 + lk * 8;
    bf16x8 a0 = (bf16x8)(short)0, a1 = (bf16x8)(short)0;
    if (ok0) {
      const float4* xp = (const float4*)(x + (size_t)r0 * 128 + k0);
      float4 v0 = xp[0], v1 = xp[1];
      a0[0] = (short)f2bf(v0.x); a0[1] = (short)f2bf(v0.y);
      a0[2] = (short)f2bf(v0.z); a0[3] = (short)f2bf(v0.w);
      a0[4] = (short)f2bf(v1.x); a0[5] = (short)f2bf(v1.y);
      a0[6] = (short)f2bf(v1.z); a0[7] = (short)f2bf(v1.w);
    }
    if (ok1) {
      const float4* xp = (const float4*)(x + (size_t)r1 * 128 + k0);
      float4 v0 = xp[0], v1 = xp[1];
      a1[0] = (short)f2bf(v0.x); a1[1] = (short)f2bf(v0.y);
      a1[2] = (short)f2bf(v0.z); a1[3] = (short)f2bf(v0.w);
      a1[4] = (short)f2bf(v1.x); a1[5] = (short)f2bf(v1.y);
      a1[6] = (short)f2bf(v1.z); a1[7] = (short)f2bf(v1.w);
    }
#pragma unroll
    for (int ct = 0; ct < 8; ct++) {
      int byte = ((ct * 16 + lr) * 128 + k0) * 2;
      byte ^= swz;
      bf16x8 b = *(const bf16x8*)((const char*)wT + byte);
      acc[0][ct] = __builtin_amdgcn_mfma_f32_16x16x32_bf16(a0, b, acc[0][ct], 0, 0, 0);
      acc[1][ct] = __builtin_amdgcn_mfma_f32_16x16x32_bf16(a1, b, acc[1][ct], 0, 0, 0);
    }
  }

  float bias[4];
#pragma unroll
  for (int q = 0; q < 4; q++) bias[q] = pb[q * 16 + lr];

#pragma unroll
  for (int rt = 0; rt < 2; rt++) {
#pragma unroll
    for (int e = 0; e < 4; e++) {
      int r = rowBase + rt * 16 + lk * 4 + e;
      if (r >= n) continue;
#pragma unroll
      for (int ct = 0; ct < 4; ct++)
        ob[(size_t)r * 64 + ct * 16 + lr] = f2bf(acc[rt][ct][e]);
#pragma unroll
      for (int ct = 4; ct < 8; ct++)
        of[(size_t)r * 64 + (ct - 4) * 16 + lr] = acc[rt][ct][e] + bias[ct - 4];
    }
  }
}

// ---- GEMM2 via MFMA: [n,64] @ [64,64] -> bf16 hwb. (unchanged)
__global__ __launch_bounds__(256) void k_gemm2m(
    const float* __restrict__ h, const float* __restrict__ W2,
    ushort* __restrict__ ob, int n) {
  __shared__ ushort wT[64 * 64];  // 8 KB
  int tid = threadIdx.x;
  for (int idx = tid; idx < 64 * 32; idx += 256) {
    int c = idx >> 5;
    int kp = idx & 31;
    float f0 = W2[(size_t)(2 * kp) * 64 + c];
    float f1 = W2[(size_t)(2 * kp + 1) * 64 + c];
    uint pk = (uint)f2bf(f0) | ((uint)f2bf(f1) << 16);
    int byte = c * 128 + kp * 4;
    byte ^= ((c & 7) << 4);
    *(uint*)((char*)wT + byte) = pk;
  }
  __syncthreads();

  int lane = tid & 63;
  int wv = tid >> 6;
  int lr = lane & 15;
  int lk = lane >> 4;
  int rowBase = blockIdx.x * 128 + wv * 32;

  f32x4 acc[2][4];
#pragma unroll
  for (int i = 0; i < 2; i++)
#pragma unroll
    for (int j = 0; j < 4; j++) acc[i][j] = (f32x4){0.f, 0.f, 0.f, 0.f};

  int r0 = rowBase + lr;
  int r1 = rowBase + 16 + lr;
  bool ok0 = r0 < n, ok1 = r1 < n;
  int swz = (lr & 7) << 4;

#pragma unroll
  for (int ks = 0; ks < 2; ks++) {
    int k0 = ks * 32 + lk * 8;
    bf16x8 a0 = (bf16x8)(short)0, a1 = (bf16x8)(short)0;
    if (ok0) {
      const float4* xp = (const float4*)(h + (size_t)r0 * 64 + k0);
      float4 v0 = xp[0], v1 = xp[1];
      a0[0] = (short)f2bf(v0.x); a0[1] = (short)f2bf(v0.y);
      a0[2] = (short)f2bf(v0.z); a0[3] = (short)f2bf(v0.w);
      a0[4] = (short)f2bf(v1.x); a0[5] = (short)f2bf(v1.y);
      a0[6] = (short)f2bf(v1.z); a0[7] = (short)f2bf(v1.w);
    }
    if (ok1) {
      const float4* xp = (const float4*)(h + (size_t)r1 * 64 + k0);
      float4 v0 = xp[0], v1 = xp[1];
      a1[0] = (short)f2bf(v0.x); a1[1] = (short)f2bf(v0.y);
      a1[2] = (short)f2bf(v0.z); a1[3] = (short)f2bf(v0.w);
      a1[4] = (short)f2bf(v1.x); a1[5] = (short)f2bf(v1.y);
      a1[6] = (short)f2bf(v1.z); a1[7] = (short)f2bf(v1.w);
    }
#pragma unroll
    for (int ct = 0; ct < 4; ct++) {
      int byte = ((ct * 16 + lr) * 64 + k0) * 2;
      byte ^= swz;
      bf16x8 b = *(const bf16x8*)((const char*)wT + byte);
      acc[0][ct] = __builtin_amdgcn_mfma_f32_16x16x32_bf16(a0, b, acc[0][ct], 0, 0, 0);
      acc[1][ct] = __builtin_amdgcn_mfma_f32_16x16x32_bf16(a1, b, acc[1][ct], 0, 0, 0);
    }
  }

#pragma unroll
  for (int rt = 0; rt < 2; rt++) {
#pragma unroll
    for (int e = 0; e < 4; e++) {
      int r = rowBase + rt * 16 + lk * 4 + e;
      if (r >= n) continue;
#pragma unroll
      for (int ct = 0; ct < 4; ct++)
        ob[(size_t)r * 64 + ct * 16 + lr] = f2bf(acc[rt][ct][e]);
    }
  }
}

// out = relu(g*(agg-mu)*rsqrt(var+eps)+beta) + res   (conv bias cancels in BN)
__global__ __launch_bounds__(256) void k_bnrelu(
    const float* __restrict__ agg, const float* __restrict__ res,
    const float* __restrict__ stats, const float* __restrict__ g,
    const float* __restrict__ beta, float* __restrict__ out, int n) {
  int idx = blockIdx.x * 256 + threadIdx.x;
  if (idx >= n * 16) return;
  int c4 = (idx & 15) * 4;
  float invN = 1.0f / (float)n;
  float4 a = ((const float4*)agg)[idx];
  float4 rr = ((const float4*)res)[idx];
  float av[4] = {a.x, a.y, a.z, a.w};
  float rv[4] = {rr.x, rr.y, rr.z, rr.w};
  float vo[4];
#pragma unroll
  for (int j = 0; j < 4; j++) {
    int c = c4 + j;
    float mu = stats[c] * invN;
    float var = stats[64 + c] * invN - mu * mu;
    float sc = g[c] * rsqrtf(var + BN_EPS);
    float v = (av[j] - mu) * sc + beta[c];
    vo[j] = fmaxf(v, 0.0f) + rv[j];
  }
  ((float4*)out)[idx] = make_float4(vo[0], vo[1], vo[2], vo[3]);
}

extern "C" void kernel_launch(void* const* d_in, const int* in_sizes, int n_in,
                              void* d_out, int out_size, void* d_ws, size_t ws_size,
                              hipStream_t stream) {
  const float* x = (const float*)d_in[0];
  const int* ei = (const int*)d_in[1];
  const float* ew = (const float*)d_in[2];
  const float* W1 = (const float*)d_in[3];
  const float* g1 = (const float*)d_in[5];
  const float* be1 = (const float*)d_in[6];
  const float* W2 = (const float*)d_in[7];
  const float* g2 = (const float*)d_in[9];
  const float* be2 = (const float*)d_in[10];
  const float* pW = (const float*)d_in[11];
  const float* pb = (const float*)d_in[12];

  int n = in_sizes[0] / 128;
  int e = in_sizes[1] / 2;
  const int* row = ei;      // source
  const int* col = ei + e;  // target

  // workspace layout (spair padded by 32 int2: streaming k_agg may over-READ
  // meta past a group's range; masked before use)
  float* ws = (float*)d_ws;
  float* dis = ws;                             // n
  int* ptr = (int*)(dis + n);                  // n+4
  int* cnt = ptr + n + 4;                      // n
  int* rank = cnt + n;                         // e
  int* bsum = rank + e;                        // 1024
  int2* spair = (int2*)(bsum + 1024);          // e int2 (+32 pad)
  ushort* hwb = (ushort*)(spair + e + 32);     // n*64 bf16 (hw1, then hw2)
  float* bufR = (float*)(hwb + (size_t)n * 64);  // n*64 (residual)
  float* bufB = bufR + (size_t)n * 64;         // n*64 (agg)
  float* bufA = bufB + (size_t)n * 64;         // n*64 (h)
  float* stats = bufA + (size_t)n * 64;        // 128

  float* out = (float*)d_out;

  int nb_n = (n + 255) / 256;
  int nb_e = (e + 255) / 256;
  int nb_b = (n * 16 + 255) / 256;
  int nb_sc = (n + 1023) / 1024;
  int nb_g = (n + 127) / 128;

  // k_agg geometry: 2048 blocks x 16 groups = 32768 contiguous node ranges.
  // VGPR 60 -> 8 waves/SIMD; 2048 blocks = 32 waves/CU launch residency
  // (R14's 1024 blocks averaged only 27% occupancy -> MLP-starved).
  constexpr int AGG_BLOCKS = 2048;
  int ngroups = AGG_BLOCKS * 16;
  int npg = (n + ngroups - 1) / ngroups;  // nodes per group

  // CSR build + gcn_norm
  hipMemsetAsync(cnt, 0, n * sizeof(int), stream);
  k_hist<<<nb_e, 256, 0, stream>>>(col, cnt, rank, e);
  k_scan_part<<<nb_sc, 256, 0, stream>>>(cnt, bsum, n);
  k_scan_mid<<<1, 1024, 0, stream>>>(bsum, nb_sc);
  k_scan_apply<<<nb_sc, 256, 0, stream>>>(cnt, ptr, bsum, n, e);
  k_fillcsr<<<nb_e, 256, 0, stream>>>(row, col, ew, ptr, rank, spair, e);
  k_degdis<<<nb_n, 256, 0, stream>>>(ptr, spair, dis, n);
  k_scale<<<nb_e, 256, 0, stream>>>(spair, dis, e);

  // layer 1: combined [x@W1 -> bf16 hwb | x@pW + pb -> f32 bufR]
  k_gemm1m<<<nb_g, 256, 0, stream>>>(x, W1, pW, pb, hwb, bufR, n);
  hipMemsetAsync(stats, 0, 128 * sizeof(float), stream);
  k_agg<<<AGG_BLOCKS, 256, 0, stream>>>(ptr, spair, dis, hwb, bufB, stats, n, npg);
  k_bnrelu<<<nb_b, 256, 0, stream>>>(bufB, bufR, stats, g1, be1, bufA, n);

  // layer 2
  k_gemm2m<<<nb_g, 256, 0, stream>>>(bufA, W2, hwb, n);
  hipMemsetAsync(stats, 0, 128 * sizeof(float), stream);
  k_agg<<<AGG_BLOCKS, 256, 0, stream>>>(ptr, spair, dis, hwb, bufB, stats, n, npg);
  k_bnrelu<<<nb_b, 256, 0, stream>>>(bufB, bufA, stats, g2, be2, out, n);
}

// Round 16
// 388.176 us; speedup vs baseline: 1.1389x; 1.1389x over previous
//
#include <hip/hip_runtime.h>

static constexpr float BN_EPS = 1e-5f;
typedef unsigned int uint;
typedef unsigned short ushort;
typedef __attribute__((ext_vector_type(8))) short bf16x8;
typedef __attribute__((ext_vector_type(4))) float f32x4;

__device__ __forceinline__ void fatomic_add(float* p, float v) {
  unsafeAtomicAdd(p, v);  // HW global_atomic_add_f32
}

__device__ __forceinline__ ushort f2bf(float f) {  // f32 -> bf16 RNE
  uint u = __float_as_uint(f);
  u += 0x7fffu + ((u >> 16) & 1u);
  return (ushort)(u >> 16);
}

__device__ __forceinline__ float4 bf4_decode(uint2 r) {
  return make_float4(__uint_as_float(r.x << 16), __uint_as_float(r.x & 0xffff0000u),
                     __uint_as_float(r.y << 16), __uint_as_float(r.y & 0xffff0000u));
}

// ---- FUSED: GEMM1 (MFMA) + edge histogram, block-split single launch.
// Blocks [0, gB): [x@W1 -> bf16 ob | x@pW + pb -> f32 of]  (independent of hist)
// Blocks [gB, gB+hB): rank[i] = atomicAdd(&cnt[col[i]], 1)   (independent of gemm)
// The two roles use disjoint resources (MFMA+LDS vs atomic fabric) and overlap.
__global__ __launch_bounds__(256) void k_g1_hist(
    const float* __restrict__ x, const float* __restrict__ W1,
    const float* __restrict__ pW, const float* __restrict__ pb,
    ushort* __restrict__ ob, float* __restrict__ of,
    const int* __restrict__ col, int* __restrict__ cnt, int* __restrict__ rank,
    int n, int e, int gB) {
  __shared__ ushort wT[128 * 128];  // 32 KB (gemm role only)
  int tid = threadIdx.x;

  if ((int)blockIdx.x >= gB) {  // ---- histogram role
    int i = ((int)blockIdx.x - gB) * 256 + tid;
    if (i < e) rank[i] = atomicAdd(&cnt[col[i]], 1);
    return;
  }

  // ---- GEMM1 role (identical to R12-R14 k_gemm1m)
  for (int idx = tid; idx < 128 * 64; idx += 256) {
    int c = idx >> 6;
    int kp = idx & 63;
    const float* src = (c < 64) ? (W1 + c) : (pW + (c - 64));
    float f0 = src[(size_t)(2 * kp) * 64];
    float f1 = src[(size_t)(2 * kp + 1) * 64];
    uint pk = (uint)f2bf(f0) | ((uint)f2bf(f1) << 16);
    int byte = c * 256 + kp * 4;
    byte ^= ((c & 7) << 4);
    *(uint*)((char*)wT + byte) = pk;
  }
  __syncthreads();

  int lane = tid & 63;
  int wv = tid >> 6;
  int lr = lane & 15;
  int lk = lane >> 4;
  int rowBase = blockIdx.x * 128 + wv * 32;

  f32x4 acc[2][8];
#pragma unroll
  for (int i = 0; i < 2; i++)
#pragma unroll
    for (int j = 0; j < 8; j++) acc[i][j] = (f32x4){0.f, 0.f, 0.f, 0.f};

  int r0 = rowBase + lr;
  int r1 = rowBase + 16 + lr;
  bool ok0 = r0 < n, ok1 = r1 < n;
  int swz = (lr & 7) << 4;

#pragma unroll
  for (int ks = 0; ks < 4; ks++) {
    int k0 = ks * 32 + lk * 8;
    bf16x8 a0 = (bf16x8)(short)0, a1 = (bf16x8)(short)0;
    if (ok0) {
      const float4* xp = (const float4*)(x + (size_t)r0 * 128 + k0);
      float4 v0 = xp[0], v1 = xp[1];
      a0[0] = (short)f2bf(v0.x); a0[1] = (short)f2bf(v0.y);
      a0[2] = (short)f2bf(v0.z); a0[3] = (short)f2bf(v0.w);
      a0[4] = (short)f2bf(v1.x); a0[5] = (short)f2bf(v1.y);
      a0[6] = (short)f2bf(v1.z); a0[7] = (short)f2bf(v1.w);
    }
    if (ok1) {
      const float4* xp = (const float4*)(x + (size_t)r1 * 128 + k0);
      float4 v0 = xp[0], v1 = xp[1];
      a1[0] = (short)f2bf(v0.x); a1[1] = (short)f2bf(v0.y);
      a1[2] = (short)f2bf(v0.z); a1[3] = (short)f2bf(v0.w);
      a1[4] = (short)f2bf(v1.x); a1[5] = (short)f2bf(v1.y);
      a1[6] = (short)f2bf(v1.z); a1[7] = (short)f2bf(v1.w);
    }
#pragma unroll
    for (int ct = 0; ct < 8; ct++) {
      int byte = ((ct * 16 + lr) * 128 + k0) * 2;
      byte ^= swz;
      bf16x8 b = *(const bf16x8*)((const char*)wT + byte);
      acc[0][ct] = __builtin_amdgcn_mfma_f32_16x16x32_bf16(a0, b, acc[0][ct], 0, 0, 0);
      acc[1][ct] = __builtin_amdgcn_mfma_f32_16x16x32_bf16(a1, b, acc[1][ct], 0, 0, 0);
    }
  }

  float bias[4];
#pragma unroll
  for (int q = 0; q < 4; q++) bias[q] = pb[q * 16 + lr];

#pragma unroll
  for (int rt = 0; rt < 2; rt++) {
#pragma unroll
    for (int e2 = 0; e2 < 4; e2++) {
      int r = rowBase + rt * 16 + lk * 4 + e2;
      if (r >= n) continue;
#pragma unroll
      for (int ct = 0; ct < 4; ct++)
        ob[(size_t)r * 64 + ct * 16 + lr] = f2bf(acc[rt][ct][e2]);
#pragma unroll
      for (int ct = 4; ct < 8; ct++)
        of[(size_t)r * 64 + (ct - 4) * 16 + lr] = acc[rt][ct][e2] + bias[ct - 4];
    }
  }
}

// ---- device-wide exclusive scan of cnt[n] (1024 elems/block) ----
__global__ __launch_bounds__(256) void k_scan_part(const int* __restrict__ cnt,
                                                   int* __restrict__ bsum, int n) {
  __shared__ int sm[256];
  int t = threadIdx.x;
  int base = blockIdx.x * 1024 + t * 4;
  int s = 0;
#pragma unroll
  for (int j = 0; j < 4; j++) {
    int i = base + j;
    if (i < n) s += cnt[i];
  }
  sm[t] = s;
  __syncthreads();
  for (int off = 128; off > 0; off >>= 1) {
    if (t < off) sm[t] += sm[t + off];
    __syncthreads();
  }
  if (t == 0) bsum[blockIdx.x] = sm[0];
}

__global__ __launch_bounds__(1024) void k_scan_mid(int* __restrict__ bsum, int nb) {
  __shared__ int sm[1024];
  int t = threadIdx.x;
  int v = (t < nb) ? bsum[t] : 0;
  sm[t] = v;
  __syncthreads();
  for (int off = 1; off < 1024; off <<= 1) {
    int o = (t >= off) ? sm[t - off] : 0;
    __syncthreads();
    sm[t] += o;
    __syncthreads();
  }
  if (t < nb) bsum[t] = sm[t] - v;  // exclusive block offsets
}

__global__ __launch_bounds__(256) void k_scan_apply(const int* __restrict__ cnt,
                                                    int* __restrict__ ptr,
                                                    const int* __restrict__ bsum,
                                                    int n, int e) {
  __shared__ int sm[256];
  int t = threadIdx.x;
  int base = blockIdx.x * 1024 + t * 4;
  int v[4];
  int s = 0;
#pragma unroll
  for (int j = 0; j < 4; j++) {
    int i = base + j;
    v[j] = (i < n) ? cnt[i] : 0;
    s += v[j];
  }
  sm[t] = s;
  __syncthreads();
  for (int off = 1; off < 256; off <<= 1) {
    int o = (t >= off) ? sm[t - off] : 0;
    __syncthreads();
    sm[t] += o;
    __syncthreads();
  }
  int run = bsum[blockIdx.x] + sm[t] - s;
#pragma unroll
  for (int j = 0; j < 4; j++) {
    int i = base + j;
    if (i < n) {
      ptr[i] = run;
      run += v[j];
    }
  }
  if (blockIdx.x == 0 && t == 0) ptr[n] = e;
}

// atomic-free CSR fill: slot = ptr[col] + rank
__global__ void k_fillcsr(const int* __restrict__ row, const int* __restrict__ col,
                          const float* __restrict__ ew, const int* __restrict__ ptr,
                          const int* __restrict__ rank, int2* __restrict__ spair, int e) {
  int i = blockIdx.x * 256 + threadIdx.x;
  if (i >= e) return;
  int p = ptr[col[i]] + rank[i];
  spair[p] = make_int2(row[i], __float_as_int(ew[i]));
}

// per-node: deg = 1 (self-loop) + segment-sum of ew; dis = rsqrt(deg). No atomics.
__global__ void k_degdis(const int* __restrict__ ptr, const int2* __restrict__ spair,
                         float* __restrict__ dis, int n) {
  int v = blockIdx.x * 256 + threadIdx.x;
  if (v >= n) return;
  int b = ptr[v], en = ptr[v + 1];
  float s = 1.0f;
  for (int j = b; j < en; j++) s += __int_as_float(spair[j].y);
  dis[v] = rsqrtf(s);
}

// fold dis[row] into stored edge weight (dis[col] applied in k_agg)
__global__ void k_scale(int2* __restrict__ spair, const float* __restrict__ dis, int e) {
  int i = blockIdx.x * 256 + threadIdx.x;
  if (i >= e) return;
  int2 m = spair[i];
  spair[i] = make_int2(m.x, __float_as_int(__int_as_float(m.y) * dis[m.x]));
}

// ---- aggregation v5 + fused BN stats (R14 structure, R14 geometry).
__global__ __launch_bounds__(256) void k_agg(
    const int* __restrict__ ptr, const int2* __restrict__ spair,
    const float* __restrict__ dis, const ushort* __restrict__ hwb,
    float* __restrict__ agg, float* __restrict__ stats, int n, int npg) {
  int tid = threadIdx.x;
  int lane = tid & 63;
  int li = lane & 15;
  int gbase = lane & 48;  // group base lane within wave (0,16,32,48)
  int gidx = (blockIdx.x * 256 + tid) >> 4;  // global group id
  float st_s[4] = {0.f, 0.f, 0.f, 0.f};
  float st_q[4] = {0.f, 0.f, 0.f, 0.f};

  int v0 = gidx * npg;
  if (v0 < n) {
    int v1 = min(v0 + npg, n);
    int tmax = v1 - v0;  // <= npg <= 15
    // lane-parallel ptr/dis for the range
    int pv = ptr[min(v0 + li, n)];
    float dvr = dis[min(v0 + li, n - 1)];
    int begR = __shfl(pv, gbase);
    int jend = __shfl(pv, gbase + tmax);

    // node-walk state
    int v = v0, t = 0;
    float d = __shfl(dvr, gbase);
    int e_cur = __shfl(pv, gbase + 1);
    uint2 self_cur = *(const uint2*)(hwb + (size_t)v0 * 64 + li * 4);
    uint2 self_nxt = *(const uint2*)(hwb + (size_t)min(v0 + 1, n - 1) * 64 + li * 4);
    int vself = v0 + 2;
    float4 acc = make_float4(0.f, 0.f, 0.f, 0.f);

#define FINALIZE_NODE()                                                        \
  {                                                                            \
    float4 sf = bf4_decode(self_cur);                                          \
    float4 o;                                                                  \
    o.x = d * fmaf(d, sf.x, acc.x);                                            \
    o.y = d * fmaf(d, sf.y, acc.y);                                            \
    o.z = d * fmaf(d, sf.z, acc.z);                                            \
    o.w = d * fmaf(d, sf.w, acc.w);                                            \
    *(float4*)(agg + (size_t)v * 64 + li * 4) = o;                             \
    st_s[0] += o.x; st_s[1] += o.y; st_s[2] += o.z; st_s[3] += o.w;            \
    st_q[0] = fmaf(o.x, o.x, st_q[0]);                                         \
    st_q[1] = fmaf(o.y, o.y, st_q[1]);                                         \
    st_q[2] = fmaf(o.z, o.z, st_q[2]);                                         \
    st_q[3] = fmaf(o.w, o.w, st_q[3]);                                         \
    acc = make_float4(0.f, 0.f, 0.f, 0.f);                                     \
    self_cur = self_nxt;                                                       \
    self_nxt = *(const uint2*)(hwb + (size_t)min(vself, n - 1) * 64 + li * 4); \
    vself++;                                                                   \
    v++; t++;                                                                  \
    d = __shfl(dvr, gbase + min(t, 15));                                       \
    e_cur = __shfl(pv, gbase + min(t + 1, 15));                                \
  }

    if (begR < jend) {
      const int4* sp = (const int4*)spair;
      int jc = begR & ~3;
      int h = jc >> 1;
      int nch = (jend - jc + 3) >> 2;

      float wA[4], wB[4], wC_[4];
      uint2 gA[4], gB[4], gC_[4];
      int4 mN0, mN1;

      {  // prologue chunk 0
        int4 p0 = sp[h], p1 = sp[h + 1];
        int rr[4] = {p0.x, p0.z, p1.x, p1.z};
        int wi[4] = {p0.y, p0.w, p1.y, p1.w};
#pragma unroll
        for (int k = 0; k < 4; k++) {
          int j = jc + k;
          bool okk = (j >= begR) && (j < jend);
          int r = okk ? rr[k] : v0;
          wA[k] = okk ? __int_as_float(wi[k]) : 0.f;
          gA[k] = *(const uint2*)(hwb + (size_t)r * 64 + li * 4);
        }
      }
      if (nch > 1) {  // chunk 1
        int4 p0 = sp[h + 2], p1 = sp[h + 3];
        int rr[4] = {p0.x, p0.z, p1.x, p1.z};
        int wi[4] = {p0.y, p0.w, p1.y, p1.w};
#pragma unroll
        for (int k = 0; k < 4; k++) {
          bool okk = (jc + 4 + k) < jend;
          int r = okk ? rr[k] : v0;
          wB[k] = okk ? __int_as_float(wi[k]) : 0.f;
          gB[k] = *(const uint2*)(hwb + (size_t)r * 64 + li * 4);
        }
      }
      if (nch > 2) {  // chunk 2
        int4 p0 = sp[h + 4], p1 = sp[h + 5];
        int rr[4] = {p0.x, p0.z, p1.x, p1.z};
        int wi[4] = {p0.y, p0.w, p1.y, p1.w};
#pragma unroll
        for (int k = 0; k < 4; k++) {
          bool okk = (jc + 8 + k) < jend;
          int r = okk ? rr[k] : v0;
          wC_[k] = okk ? __int_as_float(wi[k]) : 0.f;
          gC_[k] = *(const uint2*)(hwb + (size_t)r * 64 + li * 4);
        }
      }
      if (nch > 3) { mN0 = sp[h + 6]; mN1 = sp[h + 7]; }

      for (int c = 0; c < nch; c++) {
        float wD[4];
        uint2 gD[4];
        if (c + 3 < nch) {  // issue gathers for chunk c+3
          int jn = jc + 12;
          int rr[4] = {mN0.x, mN0.z, mN1.x, mN1.z};
          int wi[4] = {mN0.y, mN0.w, mN1.y, mN1.w};
#pragma unroll
          for (int k = 0; k < 4; k++) {
            bool okk = (jn + k) < jend;
            int r = okk ? rr[k] : v0;
            wD[k] = okk ? __int_as_float(wi[k]) : 0.f;
            gD[k] = *(const uint2*)(hwb + (size_t)r * 64 + li * 4);
          }
        }
        if (c + 4 < nch) {  // prefetch meta for chunk c+4
          mN0 = sp[h + 2 * (c + 4)];
          mN1 = sp[h + 2 * (c + 4) + 1];
        }
        // compute chunk c with node-boundary advance
#pragma unroll
        for (int k = 0; k < 4; k++) {
          int j = jc + k;
          while (j >= e_cur && v < v1) FINALIZE_NODE();
          float4 f = bf4_decode(gA[k]);
          acc.x = fmaf(wA[k], f.x, acc.x);
          acc.y = fmaf(wA[k], f.y, acc.y);
          acc.z = fmaf(wA[k], f.z, acc.z);
          acc.w = fmaf(wA[k], f.w, acc.w);
        }
#pragma unroll
        for (int k = 0; k < 4; k++) {
          gA[k] = gB[k]; wA[k] = wB[k];
          gB[k] = gC_[k]; wB[k] = wC_[k];
        }
        if (c + 3 < nch) {
#pragma unroll
          for (int k = 0; k < 4; k++) { gC_[k] = gD[k]; wC_[k] = wD[k]; }
        }
        jc += 4;
      }
    }
    // epilogue: finalize remaining nodes (incl. zero-degree / tail)
    while (v < v1) FINALIZE_NODE();
#undef FINALIZE_NODE
  }

  // cross-group + block stats reduction
#pragma unroll
  for (int j = 0; j < 4; j++) {
    st_s[j] += __shfl_xor(st_s[j], 16);
    st_s[j] += __shfl_xor(st_s[j], 32);
    st_q[j] += __shfl_xor(st_q[j], 16);
    st_q[j] += __shfl_xor(st_q[j], 32);
  }
  __shared__ float rs[4][64];
  __shared__ float rq[4][64];
  int wv = tid >> 6;
  if (gbase == 0) {
#pragma unroll
    for (int j = 0; j < 4; j++) {
      rs[wv][li * 4 + j] = st_s[j];
      rq[wv][li * 4 + j] = st_q[j];
    }
  }
  __syncthreads();
  if (tid < 64) {
    int c = tid;
    float s = rs[0][c] + rs[1][c] + rs[2][c] + rs[3][c];
    float q = rq[0][c] + rq[1][c] + rq[2][c] + rq[3][c];
    fatomic_add(&stats[c], s);
    fatomic_add(&stats[64 + c], q);
  }
}

// ---- GEMM2 via MFMA: [n,64] @ [64,64] -> bf16 hwb. (unchanged)
__global__ __launch_bounds__(256) void k_gemm2m(
    const float* __restrict__ h, const float* __restrict__ W2,
    ushort* __restrict__ ob, int n) {
  __shared__ ushort wT[64 * 64];  // 8 KB
  int tid = threadIdx.x;
  for (int idx = tid; idx < 64 * 32; idx += 256) {
    int c = idx >> 5;
    int kp = idx & 31;
    float f0 = W2[(size_t)(2 * kp) * 64 + c];
    float f1 = W2[(size_t)(2 * kp + 1) * 64 + c];
    uint pk = (uint)f2bf(f0) | ((uint)f2bf(f1) << 16);
    int byte = c * 128 + kp * 4;
    byte ^= ((c & 7) << 4);
    *(uint*)((char*)wT + byte) = pk;
  }
  __syncthreads();

  int lane = tid & 63;
  int wv = tid >> 6;
  int lr = lane & 15;
  int lk = lane >> 4;
  int rowBase = blockIdx.x * 128 + wv * 32;

  f32x4 acc[2][4];
#pragma unroll
  for (int i = 0; i < 2; i++)
#pragma unroll
    for (int j = 0; j < 4; j++) acc[i][j] = (f32x4){0.f, 0.f, 0.f, 0.f};

  int r0 = rowBase + lr;
  int r1 = rowBase + 16 + lr;
  bool ok0 = r0 < n, ok1 = r1 < n;
  int swz = (lr & 7) << 4;

#pragma unroll
  for (int ks = 0; ks < 2; ks++) {
    int k0 = ks * 32 + lk * 8;
    bf16x8 a0 = (bf16x8)(short)0, a1 = (bf16x8)(short)0;
    if (ok0) {
      const float4* xp = (const float4*)(h + (size_t)r0 * 64 + k0);
      float4 v0 = xp[0], v1 = xp[1];
      a0[0] = (short)f2bf(v0.x); a0[1] = (short)f2bf(v0.y);
      a0[2] = (short)f2bf(v0.z); a0[3] = (short)f2bf(v0.w);
      a0[4] = (short)f2bf(v1.x); a0[5] = (short)f2bf(v1.y);
      a0[6] = (short)f2bf(v1.z); a0[7] = (short)f2bf(v1.w);
    }
    if (ok1) {
      const float4* xp = (const float4*)(h + (size_t)r1 * 64 + k0);
      float4 v0 = xp[0], v1 = xp[1];
      a1[0] = (short)f2bf(v0.x); a1[1] = (short)f2bf(v0.y);
      a1[2] = (short)f2bf(v0.z); a1[3] = (short)f2bf(v0.w);
      a1[4] = (short)f2bf(v1.x); a1[5] = (short)f2bf(v1.y);
      a1[6] = (short)f2bf(v1.z); a1[7] = (short)f2bf(v1.w);
    }
#pragma unroll
    for (int ct = 0; ct < 4; ct++) {
      int byte = ((ct * 16 + lr) * 64 + k0) * 2;
      byte ^= swz;
      bf16x8 b = *(const bf16x8*)((const char*)wT + byte);
      acc[0][ct] = __builtin_amdgcn_mfma_f32_16x16x32_bf16(a0, b, acc[0][ct], 0, 0, 0);
      acc[1][ct] = __builtin_amdgcn_mfma_f32_16x16x32_bf16(a1, b, acc[1][ct], 0, 0, 0);
    }
  }

#pragma unroll
  for (int rt = 0; rt < 2; rt++) {
#pragma unroll
    for (int e = 0; e < 4; e++) {
      int r = rowBase + rt * 16 + lk * 4 + e;
      if (r >= n) continue;
#pragma unroll
      for (int ct = 0; ct < 4; ct++)
        ob[(size_t)r * 64 + ct * 16 + lr] = f2bf(acc[rt][ct][e]);
    }
  }
}

// out = relu(g*(agg-mu)*rsqrt(var+eps)+beta) + res   (conv bias cancels in BN)
__global__ __launch_bounds__(256) void k_bnrelu(
    const float* __restrict__ agg, const float* __restrict__ res,
    const float* __restrict__ stats, const float* __restrict__ g,
    const float* __restrict__ beta, float* __restrict__ out, int n) {
  int idx = blockIdx.x * 256 + threadIdx.x;
  if (idx >= n * 16) return;
  int c4 = (idx & 15) * 4;
  float invN = 1.0f / (float)n;
  float4 a = ((const float4*)agg)[idx];
  float4 rr = ((const float4*)res)[idx];
  float av[4] = {a.x, a.y, a.z, a.w};
  float rv[4] = {rr.x, rr.y, rr.z, rr.w};
  float vo[4];
#pragma unroll
  for (int j = 0; j < 4; j++) {
    int c = c4 + j;
    float mu = stats[c] * invN;
    float var = stats[64 + c] * invN - mu * mu;
    float sc = g[c] * rsqrtf(var + BN_EPS);
    float v = (av[j] - mu) * sc + beta[c];
    vo[j] = fmaxf(v, 0.0f) + rv[j];
  }
  ((float4*)out)[idx] = make_float4(vo[0], vo[1], vo[2], vo[3]);
}

extern "C" void kernel_launch(void* const* d_in, const int* in_sizes, int n_in,
                              void* d_out, int out_size, void* d_ws, size_t ws_size,
                              hipStream_t stream) {
  const float* x = (const float*)d_in[0];
  const int* ei = (const int*)d_in[1];
  const float* ew = (const float*)d_in[2];
  const float* W1 = (const float*)d_in[3];
  const float* g1 = (const float*)d_in[5];
  const float* be1 = (const float*)d_in[6];
  const float* W2 = (const float*)d_in[7];
  const float* g2 = (const float*)d_in[9];
  const float* be2 = (const float*)d_in[10];
  const float* pW = (const float*)d_in[11];
  const float* pb = (const float*)d_in[12];

  int n = in_sizes[0] / 128;
  int e = in_sizes[1] / 2;
  const int* row = ei;      // source
  const int* col = ei + e;  // target

  // workspace layout (spair padded by 32 int2: streaming k_agg may over-READ
  // meta past a group's range; masked before use)
  float* ws = (float*)d_ws;
  float* dis = ws;                             // n
  int* ptr = (int*)(dis + n);                  // n+4
  int* cnt = ptr + n + 4;                      // n
  int* rank = cnt + n;                         // e
  int* bsum = rank + e;                        // 1024
  int2* spair = (int2*)(bsum + 1024);          // e int2 (+32 pad)
  ushort* hwb = (ushort*)(spair + e + 32);     // n*64 bf16 (hw1, then hw2)
  float* bufR = (float*)(hwb + (size_t)n * 64);  // n*64 (residual)
  float* bufB = bufR + (size_t)n * 64;         // n*64 (agg)
  float* bufA = bufB + (size_t)n * 64;         // n*64 (h)
  float* stats = bufA + (size_t)n * 64;        // 128

  float* out = (float*)d_out;

  int nb_n = (n + 255) / 256;
  int nb_e = (e + 255) / 256;
  int nb_b = (n * 16 + 255) / 256;
  int nb_sc = (n + 1023) / 1024;
  int nb_g = (n + 127) / 128;

  // k_agg geometry: R14's verified best — 1024 blocks x 16 groups.
  constexpr int AGG_BLOCKS = 1024;
  int ngroups = AGG_BLOCKS * 16;
  int npg = (n + ngroups - 1) / ngroups;

  // fused GEMM1 + histogram (independent work, disjoint resources)
  hipMemsetAsync(cnt, 0, n * sizeof(int), stream);
  k_g1_hist<<<nb_g + nb_e, 256, 0, stream>>>(x, W1, pW, pb, hwb, bufR,
                                             col, cnt, rank, n, e, nb_g);

  // CSR build + gcn_norm
  k_scan_part<<<nb_sc, 256, 0, stream>>>(cnt, bsum, n);
  k_scan_mid<<<1, 1024, 0, stream>>>(bsum, nb_sc);
  k_scan_apply<<<nb_sc, 256, 0, stream>>>(cnt, ptr, bsum, n, e);
  k_fillcsr<<<nb_e, 256, 0, stream>>>(row, col, ew, ptr, rank, spair, e);
  k_degdis<<<nb_n, 256, 0, stream>>>(ptr, spair, dis, n);
  k_scale<<<nb_e, 256, 0, stream>>>(spair, dis, e);

  // layer 1
  hipMemsetAsync(stats, 0, 128 * sizeof(float), stream);
  k_agg<<<AGG_BLOCKS, 256, 0, stream>>>(ptr, spair, dis, hwb, bufB, stats, n, npg);
  k_bnrelu<<<nb_b, 256, 0, stream>>>(bufB, bufR, stats, g1, be1, bufA, n);

  // layer 2
  k_gemm2m<<<nb_g, 256, 0, stream>>>(bufA, W2, hwb, n);
  hipMemsetAsync(stats, 0, 128 * sizeof(float), stream);
  k_agg<<<AGG_BLOCKS, 256, 0, stream>>>(ptr, spair, dis, hwb, bufB, stats, n, npg);
  k_bnrelu<<<nb_b, 256, 0, stream>>>(bufB, bufA, stats, g2, be2, out, n);
}

// Round 17
// 387.645 us; speedup vs baseline: 1.1404x; 1.0014x over previous
//
#include <hip/hip_runtime.h>

static constexpr float BN_EPS = 1e-5f;
typedef unsigned int uint;
typedef unsigned short ushort;
typedef __attribute__((ext_vector_type(8))) short bf16x8;
typedef __attribute__((ext_vector_type(4))) float f32x4;

__device__ __forceinline__ void fatomic_add(float* p, float v) {
  unsafeAtomicAdd(p, v);  // HW global_atomic_add_f32
}

__device__ __forceinline__ ushort f2bf(float f) {  // f32 -> bf16 RNE
  uint u = __float_as_uint(f);
  u += 0x7fffu + ((u >> 16) & 1u);
  return (ushort)(u >> 16);
}

__device__ __forceinline__ float4 bf4_decode(uint2 r) {
  return make_float4(__uint_as_float(r.x << 16), __uint_as_float(r.x & 0xffff0000u),
                     __uint_as_float(r.y << 16), __uint_as_float(r.y & 0xffff0000u));
}

// histogram keyed by col; stores each edge's arrival rank (for atomic-free fill)
__global__ void k_hist(const int* __restrict__ col, int* __restrict__ cnt,
                       int* __restrict__ rank, int e) {
  int i = blockIdx.x * 256 + threadIdx.x;
  if (i < e) rank[i] = atomicAdd(&cnt[col[i]], 1);
}

// ---- device-wide exclusive scan of cnt[n] (1024 elems/block) ----
__global__ __launch_bounds__(256) void k_scan_part(const int* __restrict__ cnt,
                                                   int* __restrict__ bsum, int n) {
  __shared__ int sm[256];
  int t = threadIdx.x;
  int base = blockIdx.x * 1024 + t * 4;
  int s = 0;
#pragma unroll
  for (int j = 0; j < 4; j++) {
    int i = base + j;
    if (i < n) s += cnt[i];
  }
  sm[t] = s;
  __syncthreads();
  for (int off = 128; off > 0; off >>= 1) {
    if (t < off) sm[t] += sm[t + off];
    __syncthreads();
  }
  if (t == 0) bsum[blockIdx.x] = sm[0];
}

__global__ __launch_bounds__(1024) void k_scan_mid(int* __restrict__ bsum, int nb) {
  __shared__ int sm[1024];
  int t = threadIdx.x;
  int v = (t < nb) ? bsum[t] : 0;
  sm[t] = v;
  __syncthreads();
  for (int off = 1; off < 1024; off <<= 1) {
    int o = (t >= off) ? sm[t - off] : 0;
    __syncthreads();
    sm[t] += o;
    __syncthreads();
  }
  if (t < nb) bsum[t] = sm[t] - v;  // exclusive block offsets
}

__global__ __launch_bounds__(256) void k_scan_apply(const int* __restrict__ cnt,
                                                    int* __restrict__ ptr,
                                                    const int* __restrict__ bsum,
                                                    int n, int e) {
  __shared__ int sm[256];
  int t = threadIdx.x;
  int base = blockIdx.x * 1024 + t * 4;
  int v[4];
  int s = 0;
#pragma unroll
  for (int j = 0; j < 4; j++) {
    int i = base + j;
    v[j] = (i < n) ? cnt[i] : 0;
    s += v[j];
  }
  sm[t] = s;
  __syncthreads();
  for (int off = 1; off < 256; off <<= 1) {
    int o = (t >= off) ? sm[t - off] : 0;
    __syncthreads();
    sm[t] += o;
    __syncthreads();
  }
  int run = bsum[blockIdx.x] + sm[t] - s;
#pragma unroll
  for (int j = 0; j < 4; j++) {
    int i = base + j;
    if (i < n) {
      ptr[i] = run;
      run += v[j];
    }
  }
  if (blockIdx.x == 0 && t == 0) ptr[n] = e;
}

// atomic-free CSR fill: slot = ptr[col] + rank
__global__ void k_fillcsr(const int* __restrict__ row, const int* __restrict__ col,
                          const float* __restrict__ ew, const int* __restrict__ ptr,
                          const int* __restrict__ rank, int2* __restrict__ spair, int e) {
  int i = blockIdx.x * 256 + threadIdx.x;
  if (i >= e) return;
  int p = ptr[col[i]] + rank[i];
  spair[p] = make_int2(row[i], __float_as_int(ew[i]));
}

// per-node: deg = 1 (self-loop) + segment-sum of ew; dis = rsqrt(deg). No atomics.
__global__ void k_degdis(const int* __restrict__ ptr, const int2* __restrict__ spair,
                         float* __restrict__ dis, int n) {
  int v = blockIdx.x * 256 + threadIdx.x;
  if (v >= n) return;
  int b = ptr[v], en = ptr[v + 1];
  float s = 1.0f;
  for (int j = b; j < en; j++) s += __int_as_float(spair[j].y);
  dis[v] = rsqrtf(s);
}

// fold dis[row] into stored edge weight (dis[col] applied in k_agg)
__global__ void k_scale(int2* __restrict__ spair, const float* __restrict__ dis, int e) {
  int i = blockIdx.x * 256 + threadIdx.x;
  if (i >= e) return;
  int2 m = spair[i];
  spair[i] = make_int2(m.x, __float_as_int(__int_as_float(m.y) * dis[m.x]));
}

// ---- aggregation v5 + fused BN stats (R14 structure + geometry).
__global__ __launch_bounds__(256) void k_agg(
    const int* __restrict__ ptr, const int2* __restrict__ spair,
    const float* __restrict__ dis, const ushort* __restrict__ hwb,
    float* __restrict__ agg, float* __restrict__ stats, int n, int npg) {
  int tid = threadIdx.x;
  int lane = tid & 63;
  int li = lane & 15;
  int gbase = lane & 48;  // group base lane within wave (0,16,32,48)
  int gidx = (blockIdx.x * 256 + tid) >> 4;  // global group id
  float st_s[4] = {0.f, 0.f, 0.f, 0.f};
  float st_q[4] = {0.f, 0.f, 0.f, 0.f};

  int v0 = gidx * npg;
  if (v0 < n) {
    int v1 = min(v0 + npg, n);
    int tmax = v1 - v0;  // <= npg <= 15
    int pv = ptr[min(v0 + li, n)];
    float dvr = dis[min(v0 + li, n - 1)];
    int begR = __shfl(pv, gbase);
    int jend = __shfl(pv, gbase + tmax);

    int v = v0, t = 0;
    float d = __shfl(dvr, gbase);
    int e_cur = __shfl(pv, gbase + 1);
    uint2 self_cur = *(const uint2*)(hwb + (size_t)v0 * 64 + li * 4);
    uint2 self_nxt = *(const uint2*)(hwb + (size_t)min(v0 + 1, n - 1) * 64 + li * 4);
    int vself = v0 + 2;
    float4 acc = make_float4(0.f, 0.f, 0.f, 0.f);

#define FINALIZE_NODE()                                                        \
  {                                                                            \
    float4 sf = bf4_decode(self_cur);                                          \
    float4 o;                                                                  \
    o.x = d * fmaf(d, sf.x, acc.x);                                            \
    o.y = d * fmaf(d, sf.y, acc.y);                                            \
    o.z = d * fmaf(d, sf.z, acc.z);                                            \
    o.w = d * fmaf(d, sf.w, acc.w);                                            \
    *(float4*)(agg + (size_t)v * 64 + li * 4) = o;                             \
    st_s[0] += o.x; st_s[1] += o.y; st_s[2] += o.z; st_s[3] += o.w;            \
    st_q[0] = fmaf(o.x, o.x, st_q[0]);                                         \
    st_q[1] = fmaf(o.y, o.y, st_q[1]);                                         \
    st_q[2] = fmaf(o.z, o.z, st_q[2]);                                         \
    st_q[3] = fmaf(o.w, o.w, st_q[3]);                                         \
    acc = make_float4(0.f, 0.f, 0.f, 0.f);                                     \
    self_cur = self_nxt;                                                       \
    self_nxt = *(const uint2*)(hwb + (size_t)min(vself, n - 1) * 64 + li * 4); \
    vself++;                                                                   \
    v++; t++;                                                                  \
    d = __shfl(dvr, gbase + min(t, 15));                                       \
    e_cur = __shfl(pv, gbase + min(t + 1, 15));                                \
  }

    if (begR < jend) {
      const int4* sp = (const int4*)spair;
      int jc = begR & ~3;
      int h = jc >> 1;
      int nch = (jend - jc + 3) >> 2;

      float wA[4], wB[4], wC_[4];
      uint2 gA[4], gB[4], gC_[4];
      int4 mN0, mN1;

      {  // prologue chunk 0
        int4 p0 = sp[h], p1 = sp[h + 1];
        int rr[4] = {p0.x, p0.z, p1.x, p1.z};
        int wi[4] = {p0.y, p0.w, p1.y, p1.w};
#pragma unroll
        for (int k = 0; k < 4; k++) {
          int j = jc + k;
          bool okk = (j >= begR) && (j < jend);
          int r = okk ? rr[k] : v0;
          wA[k] = okk ? __int_as_float(wi[k]) : 0.f;
          gA[k] = *(const uint2*)(hwb + (size_t)r * 64 + li * 4);
        }
      }
      if (nch > 1) {  // chunk 1
        int4 p0 = sp[h + 2], p1 = sp[h + 3];
        int rr[4] = {p0.x, p0.z, p1.x, p1.z};
        int wi[4] = {p0.y, p0.w, p1.y, p1.w};
#pragma unroll
        for (int k = 0; k < 4; k++) {
          bool okk = (jc + 4 + k) < jend;
          int r = okk ? rr[k] : v0;
          wB[k] = okk ? __int_as_float(wi[k]) : 0.f;
          gB[k] = *(const uint2*)(hwb + (size_t)r * 64 + li * 4);
        }
      }
      if (nch > 2) {  // chunk 2
        int4 p0 = sp[h + 4], p1 = sp[h + 5];
        int rr[4] = {p0.x, p0.z, p1.x, p1.z};
        int wi[4] = {p0.y, p0.w, p1.y, p1.w};
#pragma unroll
        for (int k = 0; k < 4; k++) {
          bool okk = (jc + 8 + k) < jend;
          int r = okk ? rr[k] : v0;
          wC_[k] = okk ? __int_as_float(wi[k]) : 0.f;
          gC_[k] = *(const uint2*)(hwb + (size_t)r * 64 + li * 4);
        }
      }
      if (nch > 3) { mN0 = sp[h + 6]; mN1 = sp[h + 7]; }

      for (int c = 0; c < nch; c++) {
        float wD[4];
        uint2 gD[4];
        if (c + 3 < nch) {  // issue gathers for chunk c+3
          int jn = jc + 12;
          int rr[4] = {mN0.x, mN0.z, mN1.x, mN1.z};
          int wi[4] = {mN0.y, mN0.w, mN1.y, mN1.w};
#pragma unroll
          for (int k = 0; k < 4; k++) {
            bool okk = (jn + k) < jend;
            int r = okk ? rr[k] : v0;
            wD[k] = okk ? __int_as_float(wi[k]) : 0.f;
            gD[k] = *(const uint2*)(hwb + (size_t)r * 64 + li * 4);
          }
        }
        if (c + 4 < nch) {  // prefetch meta for chunk c+4
          mN0 = sp[h + 2 * (c + 4)];
          mN1 = sp[h + 2 * (c + 4) + 1];
        }
#pragma unroll
        for (int k = 0; k < 4; k++) {
          int j = jc + k;
          while (j >= e_cur && v < v1) FINALIZE_NODE();
          float4 f = bf4_decode(gA[k]);
          acc.x = fmaf(wA[k], f.x, acc.x);
          acc.y = fmaf(wA[k], f.y, acc.y);
          acc.z = fmaf(wA[k], f.z, acc.z);
          acc.w = fmaf(wA[k], f.w, acc.w);
        }
#pragma unroll
        for (int k = 0; k < 4; k++) {
          gA[k] = gB[k]; wA[k] = wB[k];
          gB[k] = gC_[k]; wB[k] = wC_[k];
        }
        if (c + 3 < nch) {
#pragma unroll
          for (int k = 0; k < 4; k++) { gC_[k] = gD[k]; wC_[k] = wD[k]; }
        }
        jc += 4;
      }
    }
    while (v < v1) FINALIZE_NODE();
#undef FINALIZE_NODE
  }

  // cross-group + block stats reduction
#pragma unroll
  for (int j = 0; j < 4; j++) {
    st_s[j] += __shfl_xor(st_s[j], 16);
    st_s[j] += __shfl_xor(st_s[j], 32);
    st_q[j] += __shfl_xor(st_q[j], 16);
    st_q[j] += __shfl_xor(st_q[j], 32);
  }
  __shared__ float rs[4][64];
  __shared__ float rq[4][64];
  int wv = tid >> 6;
  if (gbase == 0) {
#pragma unroll
    for (int j = 0; j < 4; j++) {
      rs[wv][li * 4 + j] = st_s[j];
      rq[wv][li * 4 + j] = st_q[j];
    }
  }
  __syncthreads();
  if (tid < 64) {
    int c = tid;
    float s = rs[0][c] + rs[1][c] + rs[2][c] + rs[3][c];
    float q = rq[0][c] + rq[1][c] + rq[2][c] + rq[3][c];
    fatomic_add(&stats[c], s);
    fatomic_add(&stats[64 + c], q);
  }
}

// ---- GEMM1 via MFMA: [n,128] @ [128,128]. (R12 version, standalone again)
__global__ __launch_bounds__(256) void k_gemm1m(
    const float* __restrict__ x, const float* __restrict__ W1,
    const float* __restrict__ pW, const float* __restrict__ pb,
    ushort* __restrict__ ob, float* __restrict__ of, int n) {
  __shared__ ushort wT[128 * 128];  // 32 KB
  int tid = threadIdx.x;
  for (int idx = tid; idx < 128 * 64; idx += 256) {
    int c = idx >> 6;
    int kp = idx & 63;
    const float* src = (c < 64) ? (W1 + c) : (pW + (c - 64));
    float f0 = src[(size_t)(2 * kp) * 64];
    float f1 = src[(size_t)(2 * kp + 1) * 64];
    uint pk = (uint)f2bf(f0) | ((uint)f2bf(f1) << 16);
    int byte = c * 256 + kp * 4;
    byte ^= ((c & 7) << 4);
    *(uint*)((char*)wT + byte) = pk;
  }
  __syncthreads();

  int lane = tid & 63;
  int wv = tid >> 6;
  int lr = lane & 15;
  int lk = lane >> 4;
  int rowBase = blockIdx.x * 128 + wv * 32;

  f32x4 acc[2][8];
#pragma unroll
  for (int i = 0; i < 2; i++)
#pragma unroll
    for (int j = 0; j < 8; j++) acc[i][j] = (f32x4){0.f, 0.f, 0.f, 0.f};

  int r0 = rowBase + lr;
  int r1 = rowBase + 16 + lr;
  bool ok0 = r0 < n, ok1 = r1 < n;
  int swz = (lr & 7) << 4;

#pragma unroll
  for (int ks = 0; ks < 4; ks++) {
    int k0 = ks * 32 + lk * 8;
    bf16x8 a0 = (bf16x8)(short)0, a1 = (bf16x8)(short)0;
    if (ok0) {
      const float4* xp = (const float4*)(x + (size_t)r0 * 128 + k0);
      float4 v0 = xp[0], v1 = xp[1];
      a0[0] = (short)f2bf(v0.x); a0[1] = (short)f2bf(v0.y);
      a0[2] = (short)f2bf(v0.z); a0[3] = (short)f2bf(v0.w);
      a0[4] = (short)f2bf(v1.x); a0[5] = (short)f2bf(v1.y);
      a0[6] = (short)f2bf(v1.z); a0[7] = (short)f2bf(v1.w);
    }
    if (ok1) {
      const float4* xp = (const float4*)(x + (size_t)r1 * 128 + k0);
      float4 v0 = xp[0], v1 = xp[1];
      a1[0] = (short)f2bf(v0.x); a1[1] = (short)f2bf(v0.y);
      a1[2] = (short)f2bf(v0.z); a1[3] = (short)f2bf(v0.w);
      a1[4] = (short)f2bf(v1.x); a1[5] = (short)f2bf(v1.y);
      a1[6] = (short)f2bf(v1.z); a1[7] = (short)f2bf(v1.w);
    }
#pragma unroll
    for (int ct = 0; ct < 8; ct++) {
      int byte = ((ct * 16 + lr) * 128 + k0) * 2;
      byte ^= swz;
      bf16x8 b = *(const bf16x8*)((const char*)wT + byte);
      acc[0][ct] = __builtin_amdgcn_mfma_f32_16x16x32_bf16(a0, b, acc[0][ct], 0, 0, 0);
      acc[1][ct] = __builtin_amdgcn_mfma_f32_16x16x32_bf16(a1, b, acc[1][ct], 0, 0, 0);
    }
  }

  float bias[4];
#pragma unroll
  for (int q = 0; q < 4; q++) bias[q] = pb[q * 16 + lr];

#pragma unroll
  for (int rt = 0; rt < 2; rt++) {
#pragma unroll
    for (int e2 = 0; e2 < 4; e2++) {
      int r = rowBase + rt * 16 + lk * 4 + e2;
      if (r >= n) continue;
#pragma unroll
      for (int ct = 0; ct < 4; ct++)
        ob[(size_t)r * 64 + ct * 16 + lr] = f2bf(acc[rt][ct][e2]);
#pragma unroll
      for (int ct = 4; ct < 8; ct++)
        of[(size_t)r * 64 + (ct - 4) * 16 + lr] = acc[rt][ct][e2] + bias[ct - 4];
    }
  }
}

// ---- GEMM2 + fused BN1/ReLU/residual: h = relu(bn(agg)) + res computed
// in-register during the A-load (each row is loaded by exactly one block),
// written to hout (needed as bnrelu2's residual) and fed to MFMA as bf16.
// BN scale/shift table built once in LDS from stats.
__global__ __launch_bounds__(256) void k_gemm2bn(
    const float* __restrict__ agg, const float* __restrict__ res,
    const float* __restrict__ stats, const float* __restrict__ g1,
    const float* __restrict__ be1, const float* __restrict__ W2,
    float* __restrict__ hout, ushort* __restrict__ ob, int n) {
  __shared__ ushort wT[64 * 64];  // 8 KB
  __shared__ float bnS[64];
  __shared__ float bnB[64];
  int tid = threadIdx.x;
  for (int idx = tid; idx < 64 * 32; idx += 256) {
    int c = idx >> 5;
    int kp = idx & 31;
    float f0 = W2[(size_t)(2 * kp) * 64 + c];
    float f1 = W2[(size_t)(2 * kp + 1) * 64 + c];
    uint pk = (uint)f2bf(f0) | ((uint)f2bf(f1) << 16);
    int byte = c * 128 + kp * 4;
    byte ^= ((c & 7) << 4);
    *(uint*)((char*)wT + byte) = pk;
  }
  if (tid < 64) {
    float invN = 1.0f / (float)n;
    float mu = stats[tid] * invN;
    float var = stats[64 + tid] * invN - mu * mu;
    float sc = g1[tid] * rsqrtf(var + BN_EPS);
    bnS[tid] = sc;
    bnB[tid] = be1[tid] - mu * sc;
  }
  __syncthreads();

  int lane = tid & 63;
  int wv = tid >> 6;
  int lr = lane & 15;
  int lk = lane >> 4;
  int rowBase = blockIdx.x * 128 + wv * 32;

  f32x4 acc[2][4];
#pragma unroll
  for (int i = 0; i < 2; i++)
#pragma unroll
    for (int j = 0; j < 4; j++) acc[i][j] = (f32x4){0.f, 0.f, 0.f, 0.f};

  int r0 = rowBase + lr;
  int r1 = rowBase + 16 + lr;
  bool ok0 = r0 < n, ok1 = r1 < n;
  int swz = (lr & 7) << 4;

#pragma unroll
  for (int ks = 0; ks < 2; ks++) {
    int k0 = ks * 32 + lk * 8;
    float4 s0 = *(const float4*)(bnS + k0);
    float4 s1 = *(const float4*)(bnS + k0 + 4);
    float4 t0 = *(const float4*)(bnB + k0);
    float4 t1 = *(const float4*)(bnB + k0 + 4);
    bf16x8 a0 = (bf16x8)(short)0, a1 = (bf16x8)(short)0;
    if (ok0) {
      const float4* ap = (const float4*)(agg + (size_t)r0 * 64 + k0);
      const float4* rp = (const float4*)(res + (size_t)r0 * 64 + k0);
      float4 av0 = ap[0], av1 = ap[1];
      float4 rv0 = rp[0], rv1 = rp[1];
      float4 h0 = make_float4(fmaxf(av0.x * s0.x + t0.x, 0.f) + rv0.x,
                              fmaxf(av0.y * s0.y + t0.y, 0.f) + rv0.y,
                              fmaxf(av0.z * s0.z + t0.z, 0.f) + rv0.z,
                              fmaxf(av0.w * s0.w + t0.w, 0.f) + rv0.w);
      float4 h1 = make_float4(fmaxf(av1.x * s1.x + t1.x, 0.f) + rv1.x,
                              fmaxf(av1.y * s1.y + t1.y, 0.f) + rv1.y,
                              fmaxf(av1.z * s1.z + t1.z, 0.f) + rv1.z,
                              fmaxf(av1.w * s1.w + t1.w, 0.f) + rv1.w);
      float4* hp = (float4*)(hout + (size_t)r0 * 64 + k0);
      hp[0] = h0;
      hp[1] = h1;
      a0[0] = (short)f2bf(h0.x); a0[1] = (short)f2bf(h0.y);
      a0[2] = (short)f2bf(h0.z); a0[3] = (short)f2bf(h0.w);
      a0[4] = (short)f2bf(h1.x); a0[5] = (short)f2bf(h1.y);
      a0[6] = (short)f2bf(h1.z); a0[7] = (short)f2bf(h1.w);
    }
    if (ok1) {
      const float4* ap = (const float4*)(agg + (size_t)r1 * 64 + k0);
      const float4* rp = (const float4*)(res + (size_t)r1 * 64 + k0);
      float4 av0 = ap[0], av1 = ap[1];
      float4 rv0 = rp[0], rv1 = rp[1];
      float4 h0 = make_float4(fmaxf(av0.x * s0.x + t0.x, 0.f) + rv0.x,
                              fmaxf(av0.y * s0.y + t0.y, 0.f) + rv0.y,
                              fmaxf(av0.z * s0.z + t0.z, 0.f) + rv0.z,
                              fmaxf(av0.w * s0.w + t0.w, 0.f) + rv0.w);
      float4 h1 = make_float4(fmaxf(av1.x * s1.x + t1.x, 0.f) + rv1.x,
                              fmaxf(av1.y * s1.y + t1.y, 0.f) + rv1.y,
                              fmaxf(av1.z * s1.z + t1.z, 0.f) + rv1.z,
                              fmaxf(av1.w * s1.w + t1.w, 0.f) + rv1.w);
      float4* hp = (float4*)(hout + (size_t)r1 * 64 + k0);
      hp[0] = h0;
      hp[1] = h1;
      a1[0] = (short)f2bf(h0.x); a1[1] = (short)f2bf(h0.y);
      a1[2] = (short)f2bf(h0.z); a1[3] = (short)f2bf(h0.w);
      a1[4] = (short)f2bf(h1.x); a1[5] = (short)f2bf(h1.y);
      a1[6] = (short)f2bf(h1.z); a1[7] = (short)f2bf(h1.w);
    }
#pragma unroll
    for (int ct = 0; ct < 4; ct++) {
      int byte = ((ct * 16 + lr) * 64 + k0) * 2;
      byte ^= swz;
      bf16x8 b = *(const bf16x8*)((const char*)wT + byte);
      acc[0][ct] = __builtin_amdgcn_mfma_f32_16x16x32_bf16(a0, b, acc[0][ct], 0, 0, 0);
      acc[1][ct] = __builtin_amdgcn_mfma_f32_16x16x32_bf16(a1, b, acc[1][ct], 0, 0, 0);
    }
  }

#pragma unroll
  for (int rt = 0; rt < 2; rt++) {
#pragma unroll
    for (int e2 = 0; e2 < 4; e2++) {
      int r = rowBase + rt * 16 + lk * 4 + e2;
      if (r >= n) continue;
#pragma unroll
      for (int ct = 0; ct < 4; ct++)
        ob[(size_t)r * 64 + ct * 16 + lr] = f2bf(acc[rt][ct][e2]);
    }
  }
}

// out = relu(g*(agg-mu)*rsqrt(var+eps)+beta) + res   (conv bias cancels in BN)
__global__ __launch_bounds__(256) void k_bnrelu(
    const float* __restrict__ agg, const float* __restrict__ res,
    const float* __restrict__ stats, const float* __restrict__ g,
    const float* __restrict__ beta, float* __restrict__ out, int n) {
  int idx = blockIdx.x * 256 + threadIdx.x;
  if (idx >= n * 16) return;
  int c4 = (idx & 15) * 4;
  float invN = 1.0f / (float)n;
  float4 a = ((const float4*)agg)[idx];
  float4 rr = ((const float4*)res)[idx];
  float av[4] = {a.x, a.y, a.z, a.w};
  float rv[4] = {rr.x, rr.y, rr.z, rr.w};
  float vo[4];
#pragma unroll
  for (int j = 0; j < 4; j++) {
    int c = c4 + j;
    float mu = stats[c] * invN;
    float var = stats[64 + c] * invN - mu * mu;
    float sc = g[c] * rsqrtf(var + BN_EPS);
    float v = (av[j] - mu) * sc + beta[c];
    vo[j] = fmaxf(v, 0.0f) + rv[j];
  }
  ((float4*)out)[idx] = make_float4(vo[0], vo[1], vo[2], vo[3]);
}

extern "C" void kernel_launch(void* const* d_in, const int* in_sizes, int n_in,
                              void* d_out, int out_size, void* d_ws, size_t ws_size,
                              hipStream_t stream) {
  const float* x = (const float*)d_in[0];
  const int* ei = (const int*)d_in[1];
  const float* ew = (const float*)d_in[2];
  const float* W1 = (const float*)d_in[3];
  const float* g1 = (const float*)d_in[5];
  const float* be1 = (const float*)d_in[6];
  const float* W2 = (const float*)d_in[7];
  const float* g2 = (const float*)d_in[9];
  const float* be2 = (const float*)d_in[10];
  const float* pW = (const float*)d_in[11];
  const float* pb = (const float*)d_in[12];

  int n = in_sizes[0] / 128;
  int e = in_sizes[1] / 2;
  const int* row = ei;      // source
  const int* col = ei + e;  // target

  // workspace layout (spair padded by 32 int2)
  float* ws = (float*)d_ws;
  float* dis = ws;                             // n
  int* ptr = (int*)(dis + n);                  // n+4
  int* cnt = ptr + n + 4;                      // n
  int* rank = cnt + n;                         // e
  int* bsum = rank + e;                        // 1024
  int2* spair = (int2*)(bsum + 1024);          // e int2 (+32 pad)
  ushort* hwb = (ushort*)(spair + e + 32);     // n*64 bf16 (hw1, then hw2)
  float* bufR = (float*)(hwb + (size_t)n * 64);  // n*64 (residual)
  float* bufB = bufR + (size_t)n * 64;         // n*64 (agg)
  float* bufA = bufB + (size_t)n * 64;         // n*64 (h)
  float* stats = bufA + (size_t)n * 64;        // 128

  float* out = (float*)d_out;

  int nb_n = (n + 255) / 256;
  int nb_e = (e + 255) / 256;
  int nb_b = (n * 16 + 255) / 256;
  int nb_sc = (n + 1023) / 1024;
  int nb_g = (n + 127) / 128;

  // k_agg geometry: R14's verified best — 1024 blocks x 16 groups.
  constexpr int AGG_BLOCKS = 1024;
  int ngroups = AGG_BLOCKS * 16;
  int npg = (n + ngroups - 1) / ngroups;

  // CSR build + gcn_norm (gemm1 independent, placed between)
  hipMemsetAsync(cnt, 0, n * sizeof(int), stream);
  k_hist<<<nb_e, 256, 0, stream>>>(col, cnt, rank, e);
  k_gemm1m<<<nb_g, 256, 0, stream>>>(x, W1, pW, pb, hwb, bufR, n);
  k_scan_part<<<nb_sc, 256, 0, stream>>>(cnt, bsum, n);
  k_scan_mid<<<1, 1024, 0, stream>>>(bsum, nb_sc);
  k_scan_apply<<<nb_sc, 256, 0, stream>>>(cnt, ptr, bsum, n, e);
  k_fillcsr<<<nb_e, 256, 0, stream>>>(row, col, ew, ptr, rank, spair, e);
  k_degdis<<<nb_n, 256, 0, stream>>>(ptr, spair, dis, n);
  k_scale<<<nb_e, 256, 0, stream>>>(spair, dis, e);

  // layer 1 aggregation + stats
  hipMemsetAsync(stats, 0, 128 * sizeof(float), stream);
  k_agg<<<AGG_BLOCKS, 256, 0, stream>>>(ptr, spair, dis, hwb, bufB, stats, n, npg);

  // layer 2: fused bn1/relu/residual + gemm2 (writes h -> bufA, hw2 -> hwb)
  k_gemm2bn<<<nb_g, 256, 0, stream>>>(bufB, bufR, stats, g1, be1, W2, bufA, hwb, n);
  hipMemsetAsync(stats, 0, 128 * sizeof(float), stream);
  k_agg<<<AGG_BLOCKS, 256, 0, stream>>>(ptr, spair, dis, hwb, bufB, stats, n, npg);
  k_bnrelu<<<nb_b, 256, 0, stream>>>(bufB, bufA, stats, g2, be2, out, n);
}

// Round 18
// 387.185 us; speedup vs baseline: 1.1418x; 1.0012x over previous
//
#include <hip/hip_runtime.h>

static constexpr float BN_EPS = 1e-5f;
typedef unsigned int uint;
typedef unsigned short ushort;
typedef __attribute__((ext_vector_type(8))) short bf16x8;
typedef __attribute__((ext_vector_type(4))) float f32x4;

__device__ __forceinline__ void fatomic_add(float* p, float v) {
  unsafeAtomicAdd(p, v);  // HW global_atomic_add_f32
}

__device__ __forceinline__ ushort f2bf(float f) {  // f32 -> bf16 RNE
  uint u = __float_as_uint(f);
  u += 0x7fffu + ((u >> 16) & 1u);
  return (ushort)(u >> 16);
}

__device__ __forceinline__ float4 bf4_decode(uint2 r) {
  return make_float4(__uint_as_float(r.x << 16), __uint_as_float(r.x & 0xffff0000u),
                     __uint_as_float(r.y << 16), __uint_as_float(r.y & 0xffff0000u));
}

// histogram keyed by col; stores each edge's arrival rank (for atomic-free fill)
__global__ void k_hist(const int* __restrict__ col, int* __restrict__ cnt,
                       int* __restrict__ rank, int e) {
  int i = blockIdx.x * 256 + threadIdx.x;
  if (i < e) rank[i] = atomicAdd(&cnt[col[i]], 1);
}

// ---- device-wide exclusive scan of cnt[n] (1024 elems/block) ----
__global__ __launch_bounds__(256) void k_scan_part(const int* __restrict__ cnt,
                                                   int* __restrict__ bsum, int n) {
  __shared__ int sm[256];
  int t = threadIdx.x;
  int base = blockIdx.x * 1024 + t * 4;
  int s = 0;
#pragma unroll
  for (int j = 0; j < 4; j++) {
    int i = base + j;
    if (i < n) s += cnt[i];
  }
  sm[t] = s;
  __syncthreads();
  for (int off = 128; off > 0; off >>= 1) {
    if (t < off) sm[t] += sm[t + off];
    __syncthreads();
  }
  if (t == 0) bsum[blockIdx.x] = sm[0];
}

__global__ __launch_bounds__(1024) void k_scan_mid(int* __restrict__ bsum, int nb) {
  __shared__ int sm[1024];
  int t = threadIdx.x;
  int v = (t < nb) ? bsum[t] : 0;
  sm[t] = v;
  __syncthreads();
  for (int off = 1; off < 1024; off <<= 1) {
    int o = (t >= off) ? sm[t - off] : 0;
    __syncthreads();
    sm[t] += o;
    __syncthreads();
  }
  if (t < nb) bsum[t] = sm[t] - v;  // exclusive block offsets
}

__global__ __launch_bounds__(256) void k_scan_apply(const int* __restrict__ cnt,
                                                    int* __restrict__ ptr,
                                                    const int* __restrict__ bsum,
                                                    int n, int e) {
  __shared__ int sm[256];
  int t = threadIdx.x;
  int base = blockIdx.x * 1024 + t * 4;
  int v[4];
  int s = 0;
#pragma unroll
  for (int j = 0; j < 4; j++) {
    int i = base + j;
    v[j] = (i < n) ? cnt[i] : 0;
    s += v[j];
  }
  sm[t] = s;
  __syncthreads();
  for (int off = 1; off < 256; off <<= 1) {
    int o = (t >= off) ? sm[t - off] : 0;
    __syncthreads();
    sm[t] += o;
    __syncthreads();
  }
  int run = bsum[blockIdx.x] + sm[t] - s;
#pragma unroll
  for (int j = 0; j < 4; j++) {
    int i = base + j;
    if (i < n) {
      ptr[i] = run;
      run += v[j];
    }
  }
  if (blockIdx.x == 0 && t == 0) ptr[n] = e;
}

// atomic-free CSR fill: slot = ptr[col] + rank
__global__ void k_fillcsr(const int* __restrict__ row, const int* __restrict__ col,
                          const float* __restrict__ ew, const int* __restrict__ ptr,
                          const int* __restrict__ rank, int2* __restrict__ spair, int e) {
  int i = blockIdx.x * 256 + threadIdx.x;
  if (i >= e) return;
  int p = ptr[col[i]] + rank[i];
  spair[p] = make_int2(row[i], __float_as_int(ew[i]));
}

// per-node: deg = 1 (self-loop) + segment-sum of ew; dis = rsqrt(deg). No atomics.
__global__ void k_degdis(const int* __restrict__ ptr, const int2* __restrict__ spair,
                         float* __restrict__ dis, int n) {
  int v = blockIdx.x * 256 + threadIdx.x;
  if (v >= n) return;
  int b = ptr[v], en = ptr[v + 1];
  float s = 1.0f;
  for (int j = b; j < en; j++) s += __int_as_float(spair[j].y);
  dis[v] = rsqrtf(s);
}

// fold dis[row] into stored edge weight (dis[col] applied in k_agg)
__global__ void k_scale(int2* __restrict__ spair, const float* __restrict__ dis, int e) {
  int i = blockIdx.x * 256 + threadIdx.x;
  if (i >= e) return;
  int2 m = spair[i];
  spair[i] = make_int2(m.x, __float_as_int(__int_as_float(m.y) * dis[m.x]));
}

// ---- aggregation v6 + fused BN stats.
// R14's streaming structure, but the depth-3 pipeline uses FOUR static slots
// with a 4-phase unrolled loop: at step c, issue chunk c+3 into the slot just
// freed and compute slot c%4. Zero register rotation (all indices static).
__global__ __launch_bounds__(256) void k_agg(
    const int* __restrict__ ptr, const int2* __restrict__ spair,
    const float* __restrict__ dis, const ushort* __restrict__ hwb,
    float* __restrict__ agg, float* __restrict__ stats, int n, int npg) {
  int tid = threadIdx.x;
  int lane = tid & 63;
  int li = lane & 15;
  int gbase = lane & 48;  // group base lane within wave (0,16,32,48)
  int gidx = (blockIdx.x * 256 + tid) >> 4;  // global group id
  float st_s[4] = {0.f, 0.f, 0.f, 0.f};
  float st_q[4] = {0.f, 0.f, 0.f, 0.f};

  int v0 = gidx * npg;
  if (v0 < n) {
    int v1 = min(v0 + npg, n);
    int tmax = v1 - v0;  // <= npg <= 15
    int pv = ptr[min(v0 + li, n)];
    float dvr = dis[min(v0 + li, n - 1)];
    int begR = __shfl(pv, gbase);
    int jend = __shfl(pv, gbase + tmax);

    int v = v0, t = 0;
    float d = __shfl(dvr, gbase);
    int e_cur = __shfl(pv, gbase + 1);
    uint2 self_cur = *(const uint2*)(hwb + (size_t)v0 * 64 + li * 4);
    uint2 self_nxt = *(const uint2*)(hwb + (size_t)min(v0 + 1, n - 1) * 64 + li * 4);
    int vself = v0 + 2;
    float4 acc = make_float4(0.f, 0.f, 0.f, 0.f);

#define FINALIZE_NODE()                                                        \
  {                                                                            \
    float4 sf = bf4_decode(self_cur);                                          \
    float4 o;                                                                  \
    o.x = d * fmaf(d, sf.x, acc.x);                                            \
    o.y = d * fmaf(d, sf.y, acc.y);                                            \
    o.z = d * fmaf(d, sf.z, acc.z);                                            \
    o.w = d * fmaf(d, sf.w, acc.w);                                            \
    *(float4*)(agg + (size_t)v * 64 + li * 4) = o;                             \
    st_s[0] += o.x; st_s[1] += o.y; st_s[2] += o.z; st_s[3] += o.w;            \
    st_q[0] = fmaf(o.x, o.x, st_q[0]);                                         \
    st_q[1] = fmaf(o.y, o.y, st_q[1]);                                         \
    st_q[2] = fmaf(o.z, o.z, st_q[2]);                                         \
    st_q[3] = fmaf(o.w, o.w, st_q[3]);                                         \
    acc = make_float4(0.f, 0.f, 0.f, 0.f);                                     \
    self_cur = self_nxt;                                                       \
    self_nxt = *(const uint2*)(hwb + (size_t)min(vself, n - 1) * 64 + li * 4); \
    vself++;                                                                   \
    v++; t++;                                                                  \
    d = __shfl(dvr, gbase + min(t, 15));                                       \
    e_cur = __shfl(pv, gbase + min(t + 1, 15));                                \
  }

    if (begR < jend) {
      const int4* sp = (const int4*)spair;
      int jc0 = begR & ~3;   // immutable base of chunk 0
      int jc = jc0;          // walking edge index
      int h = jc0 >> 1;
      int nch = (jend - jc0 + 3) >> 2;

      // four static slots
      float w0_[4], w1_[4], w2_[4], w3_[4];
      uint2 g0_[4], g1_[4], g2_[4], g3_[4];
      int4 mN0, mN1;  // meta for the next chunk to be issued

      {  // prologue chunk 0 (head+tail mask)
        int4 p0 = sp[h], p1 = sp[h + 1];
        int rr[4] = {p0.x, p0.z, p1.x, p1.z};
        int wi[4] = {p0.y, p0.w, p1.y, p1.w};
#pragma unroll
        for (int k = 0; k < 4; k++) {
          int j = jc0 + k;
          bool okk = (j >= begR) && (j < jend);
          int r = okk ? rr[k] : v0;
          w0_[k] = okk ? __int_as_float(wi[k]) : 0.f;
          g0_[k] = *(const uint2*)(hwb + (size_t)r * 64 + li * 4);
        }
      }
      if (nch > 1) {  // prologue chunk 1
        int4 p0 = sp[h + 2], p1 = sp[h + 3];
        int rr[4] = {p0.x, p0.z, p1.x, p1.z};
        int wi[4] = {p0.y, p0.w, p1.y, p1.w};
#pragma unroll
        for (int k = 0; k < 4; k++) {
          bool okk = (jc0 + 4 + k) < jend;
          int r = okk ? rr[k] : v0;
          w1_[k] = okk ? __int_as_float(wi[k]) : 0.f;
          g1_[k] = *(const uint2*)(hwb + (size_t)r * 64 + li * 4);
        }
      }
      if (nch > 2) {  // prologue chunk 2
        int4 p0 = sp[h + 4], p1 = sp[h + 5];
        int rr[4] = {p0.x, p0.z, p1.x, p1.z};
        int wi[4] = {p0.y, p0.w, p1.y, p1.w};
#pragma unroll
        for (int k = 0; k < 4; k++) {
          bool okk = (jc0 + 8 + k) < jend;
          int r = okk ? rr[k] : v0;
          w2_[k] = okk ? __int_as_float(wi[k]) : 0.f;
          g2_[k] = *(const uint2*)(hwb + (size_t)r * 64 + li * 4);
        }
      }
      if (nch > 3) { mN0 = sp[h + 6]; mN1 = sp[h + 7]; }

// issue gathers for chunk CC into slot (gS,wS); then prefetch meta for CC+1
#define ISSUE(gS, wS, CC)                                                      \
  {                                                                            \
    int cc_ = (CC);                                                            \
    if (cc_ < nch) {                                                           \
      int jn = jc0 + cc_ * 4;                                                  \
      int rr[4] = {mN0.x, mN0.z, mN1.x, mN1.z};                                \
      int wi[4] = {mN0.y, mN0.w, mN1.y, mN1.w};                                \
      _Pragma("unroll") for (int k = 0; k < 4; k++) {                          \
        bool okk = (jn + k) < jend;                                            \
        int r = okk ? rr[k] : v0;                                              \
        wS[k] = okk ? __int_as_float(wi[k]) : 0.f;                             \
        gS[k] = *(const uint2*)(hwb + (size_t)r * 64 + li * 4);                \
      }                                                                        \
      if (cc_ + 1 < nch) {                                                     \
        mN0 = sp[h + 2 * (cc_ + 1)];                                           \
        mN1 = sp[h + 2 * (cc_ + 1) + 1];                                       \
      }                                                                        \
    }                                                                          \
  }

// compute one chunk from slot (gS,wS) with node-boundary advance
#define COMPUTE(gS, wS)                                                        \
  {                                                                            \
    _Pragma("unroll") for (int k = 0; k < 4; k++) {                            \
      int j = jc + k;                                                          \
      while (j >= e_cur && v < v1) FINALIZE_NODE();                            \
      float4 f = bf4_decode(gS[k]);                                            \
      acc.x = fmaf(wS[k], f.x, acc.x);                                         \
      acc.y = fmaf(wS[k], f.y, acc.y);                                         \
      acc.z = fmaf(wS[k], f.z, acc.z);                                         \
      acc.w = fmaf(wS[k], f.w, acc.w);                                         \
    }                                                                          \
    jc += 4;                                                                   \
  }

      int c = 0;
      for (;;) {
        ISSUE(g3_, w3_, c + 3);
        COMPUTE(g0_, w0_);
        if (++c >= nch) break;
        ISSUE(g0_, w0_, c + 3);
        COMPUTE(g1_, w1_);
        if (++c >= nch) break;
        ISSUE(g1_, w1_, c + 3);
        COMPUTE(g2_, w2_);
        if (++c >= nch) break;
        ISSUE(g2_, w2_, c + 3);
        COMPUTE(g3_, w3_);
        if (++c >= nch) break;
      }
#undef ISSUE
#undef COMPUTE
    }
    // epilogue: finalize remaining nodes (incl. zero-degree / tail)
    while (v < v1) FINALIZE_NODE();
#undef FINALIZE_NODE
  }

  // cross-group + block stats reduction
#pragma unroll
  for (int j = 0; j < 4; j++) {
    st_s[j] += __shfl_xor(st_s[j], 16);
    st_s[j] += __shfl_xor(st_s[j], 32);
    st_q[j] += __shfl_xor(st_q[j], 16);
    st_q[j] += __shfl_xor(st_q[j], 32);
  }
  __shared__ float rs[4][64];
  __shared__ float rq[4][64];
  int wv = tid >> 6;
  if (gbase == 0) {
#pragma unroll
    for (int j = 0; j < 4; j++) {
      rs[wv][li * 4 + j] = st_s[j];
      rq[wv][li * 4 + j] = st_q[j];
    }
  }
  __syncthreads();
  if (tid < 64) {
    int c = tid;
    float s = rs[0][c] + rs[1][c] + rs[2][c] + rs[3][c];
    float q = rq[0][c] + rq[1][c] + rq[2][c] + rq[3][c];
    fatomic_add(&stats[c], s);
    fatomic_add(&stats[64 + c], q);
  }
}

// ---- GEMM1 via MFMA: [n,128] @ [128,128]. (unchanged)
__global__ __launch_bounds__(256) void k_gemm1m(
    const float* __restrict__ x, const float* __restrict__ W1,
    const float* __restrict__ pW, const float* __restrict__ pb,
    ushort* __restrict__ ob, float* __restrict__ of, int n) {
  __shared__ ushort wT[128 * 128];  // 32 KB
  int tid = threadIdx.x;
  for (int idx = tid; idx < 128 * 64; idx += 256) {
    int c = idx >> 6;
    int kp = idx & 63;
    const float* src = (c < 64) ? (W1 + c) : (pW + (c - 64));
    float f0 = src[(size_t)(2 * kp) * 64];
    float f1 = src[(size_t)(2 * kp + 1) * 64];
    uint pk = (uint)f2bf(f0) | ((uint)f2bf(f1) << 16);
    int byte = c * 256 + kp * 4;
    byte ^= ((c & 7) << 4);
    *(uint*)((char*)wT + byte) = pk;
  }
  __syncthreads();

  int lane = tid & 63;
  int wv = tid >> 6;
  int lr = lane & 15;
  int lk = lane >> 4;
  int rowBase = blockIdx.x * 128 + wv * 32;

  f32x4 acc[2][8];
#pragma unroll
  for (int i = 0; i < 2; i++)
#pragma unroll
    for (int j = 0; j < 8; j++) acc[i][j] = (f32x4){0.f, 0.f, 0.f, 0.f};

  int r0 = rowBase + lr;
  int r1 = rowBase + 16 + lr;
  bool ok0 = r0 < n, ok1 = r1 < n;
  int swz = (lr & 7) << 4;

#pragma unroll
  for (int ks = 0; ks < 4; ks++) {
    int k0 = ks * 32 + lk * 8;
    bf16x8 a0 = (bf16x8)(short)0, a1 = (bf16x8)(short)0;
    if (ok0) {
      const float4* xp = (const float4*)(x + (size_t)r0 * 128 + k0);
      float4 v0 = xp[0], v1 = xp[1];
      a0[0] = (short)f2bf(v0.x); a0[1] = (short)f2bf(v0.y);
      a0[2] = (short)f2bf(v0.z); a0[3] = (short)f2bf(v0.w);
      a0[4] = (short)f2bf(v1.x); a0[5] = (short)f2bf(v1.y);
      a0[6] = (short)f2bf(v1.z); a0[7] = (short)f2bf(v1.w);
    }
    if (ok1) {
      const float4* xp = (const float4*)(x + (size_t)r1 * 128 + k0);
      float4 v0 = xp[0], v1 = xp[1];
      a1[0] = (short)f2bf(v0.x); a1[1] = (short)f2bf(v0.y);
      a1[2] = (short)f2bf(v0.z); a1[3] = (short)f2bf(v0.w);
      a1[4] = (short)f2bf(v1.x); a1[5] = (short)f2bf(v1.y);
      a1[6] = (short)f2bf(v1.z); a1[7] = (short)f2bf(v1.w);
    }
#pragma unroll
    for (int ct = 0; ct < 8; ct++) {
      int byte = ((ct * 16 + lr) * 128 + k0) * 2;
      byte ^= swz;
      bf16x8 b = *(const bf16x8*)((const char*)wT + byte);
      acc[0][ct] = __builtin_amdgcn_mfma_f32_16x16x32_bf16(a0, b, acc[0][ct], 0, 0, 0);
      acc[1][ct] = __builtin_amdgcn_mfma_f32_16x16x32_bf16(a1, b, acc[1][ct], 0, 0, 0);
    }
  }

  float bias[4];
#pragma unroll
  for (int q = 0; q < 4; q++) bias[q] = pb[q * 16 + lr];

#pragma unroll
  for (int rt = 0; rt < 2; rt++) {
#pragma unroll
    for (int e2 = 0; e2 < 4; e2++) {
      int r = rowBase + rt * 16 + lk * 4 + e2;
      if (r >= n) continue;
#pragma unroll
      for (int ct = 0; ct < 4; ct++)
        ob[(size_t)r * 64 + ct * 16 + lr] = f2bf(acc[rt][ct][e2]);
#pragma unroll
      for (int ct = 4; ct < 8; ct++)
        of[(size_t)r * 64 + (ct - 4) * 16 + lr] = acc[rt][ct][e2] + bias[ct - 4];
    }
  }
}

// ---- GEMM2 + fused BN1/ReLU/residual (unchanged from R17)
__global__ __launch_bounds__(256) void k_gemm2bn(
    const float* __restrict__ agg, const float* __restrict__ res,
    const float* __restrict__ stats, const float* __restrict__ g1,
    const float* __restrict__ be1, const float* __restrict__ W2,
    float* __restrict__ hout, ushort* __restrict__ ob, int n) {
  __shared__ ushort wT[64 * 64];  // 8 KB
  __shared__ float bnS[64];
  __shared__ float bnB[64];
  int tid = threadIdx.x;
  for (int idx = tid; idx < 64 * 32; idx += 256) {
    int c = idx >> 5;
    int kp = idx & 31;
    float f0 = W2[(size_t)(2 * kp) * 64 + c];
    float f1 = W2[(size_t)(2 * kp + 1) * 64 + c];
    uint pk = (uint)f2bf(f0) | ((uint)f2bf(f1) << 16);
    int byte = c * 128 + kp * 4;
    byte ^= ((c & 7) << 4);
    *(uint*)((char*)wT + byte) = pk;
  }
  if (tid < 64) {
    float invN = 1.0f / (float)n;
    float mu = stats[tid] * invN;
    float var = stats[64 + tid] * invN - mu * mu;
    float sc = g1[tid] * rsqrtf(var + BN_EPS);
    bnS[tid] = sc;
    bnB[tid] = be1[tid] - mu * sc;
  }
  __syncthreads();

  int lane = tid & 63;
  int wv = tid >> 6;
  int lr = lane & 15;
  int lk = lane >> 4;
  int rowBase = blockIdx.x * 128 + wv * 32;

  f32x4 acc[2][4];
#pragma unroll
  for (int i = 0; i < 2; i++)
#pragma unroll
    for (int j = 0; j < 4; j++) acc[i][j] = (f32x4){0.f, 0.f, 0.f, 0.f};

  int r0 = rowBase + lr;
  int r1 = rowBase + 16 + lr;
  bool ok0 = r0 < n, ok1 = r1 < n;
  int swz = (lr & 7) << 4;

#pragma unroll
  for (int ks = 0; ks < 2; ks++) {
    int k0 = ks * 32 + lk * 8;
    float4 s0 = *(const float4*)(bnS + k0);
    float4 s1 = *(const float4*)(bnS + k0 + 4);
    float4 t0 = *(const float4*)(bnB + k0);
    float4 t1 = *(const float4*)(bnB + k0 + 4);
    bf16x8 a0 = (bf16x8)(short)0, a1 = (bf16x8)(short)0;
    if (ok0) {
      const float4* ap = (const float4*)(agg + (size_t)r0 * 64 + k0);
      const float4* rp = (const float4*)(res + (size_t)r0 * 64 + k0);
      float4 av0 = ap[0], av1 = ap[1];
      float4 rv0 = rp[0], rv1 = rp[1];
      float4 h0 = make_float4(fmaxf(av0.x * s0.x + t0.x, 0.f) + rv0.x,
                              fmaxf(av0.y * s0.y + t0.y, 0.f) + rv0.y,
                              fmaxf(av0.z * s0.z + t0.z, 0.f) + rv0.z,
                              fmaxf(av0.w * s0.w + t0.w, 0.f) + rv0.w);
      float4 h1 = make_float4(fmaxf(av1.x * s1.x + t1.x, 0.f) + rv1.x,
                              fmaxf(av1.y * s1.y + t1.y, 0.f) + rv1.y,
                              fmaxf(av1.z * s1.z + t1.z, 0.f) + rv1.z,
                              fmaxf(av1.w * s1.w + t1.w, 0.f) + rv1.w);
      float4* hp = (float4*)(hout + (size_t)r0 * 64 + k0);
      hp[0] = h0;
      hp[1] = h1;
      a0[0] = (short)f2bf(h0.x); a0[1] = (short)f2bf(h0.y);
      a0[2] = (short)f2bf(h0.z); a0[3] = (short)f2bf(h0.w);
      a0[4] = (short)f2bf(h1.x); a0[5] = (short)f2bf(h1.y);
      a0[6] = (short)f2bf(h1.z); a0[7] = (short)f2bf(h1.w);
    }
    if (ok1) {
      const float4* ap = (const float4*)(agg + (size_t)r1 * 64 + k0);
      const float4* rp = (const float4*)(res + (size_t)r1 * 64 + k0);
      float4 av0 = ap[0], av1 = ap[1];
      float4 rv0 = rp[0], rv1 = rp[1];
      float4 h0 = make_float4(fmaxf(av0.x * s0.x + t0.x, 0.f) + rv0.x,
                              fmaxf(av0.y * s0.y + t0.y, 0.f) + rv0.y,
                              fmaxf(av0.z * s0.z + t0.z, 0.f) + rv0.z,
                              fmaxf(av0.w * s0.w + t0.w, 0.f) + rv0.w);
      float4 h1 = make_float4(fmaxf(av1.x * s1.x + t1.x, 0.f) + rv1.x,
                              fmaxf(av1.y * s1.y + t1.y, 0.f) + rv1.y,
                              fmaxf(av1.z * s1.z + t1.z, 0.f) + rv1.z,
                              fmaxf(av1.w * s1.w + t1.w, 0.f) + rv1.w);
      float4* hp = (float4*)(hout + (size_t)r1 * 64 + k0);
      hp[0] = h0;
      hp[1] = h1;
      a1[0] = (short)f2bf(h0.x); a1[1] = (short)f2bf(h0.y);
      a1[2] = (short)f2bf(h0.z); a1[3] = (short)f2bf(h0.w);
      a1[4] = (short)f2bf(h1.x); a1[5] = (short)f2bf(h1.y);
      a1[6] = (short)f2bf(h1.z); a1[7] = (short)f2bf(h1.w);
    }
#pragma unroll
    for (int ct = 0; ct < 4; ct++) {
      int byte = ((ct * 16 + lr) * 64 + k0) * 2;
      byte ^= swz;
      bf16x8 b = *(const bf16x8*)((const char*)wT + byte);
      acc[0][ct] = __builtin_amdgcn_mfma_f32_16x16x32_bf16(a0, b, acc[0][ct], 0, 0, 0);
      acc[1][ct] = __builtin_amdgcn_mfma_f32_16x16x32_bf16(a1, b, acc[1][ct], 0, 0, 0);
    }
  }

#pragma unroll
  for (int rt = 0; rt < 2; rt++) {
#pragma unroll
    for (int e2 = 0; e2 < 4; e2++) {
      int r = rowBase + rt * 16 + lk * 4 + e2;
      if (r >= n) continue;
#pragma unroll
      for (int ct = 0; ct < 4; ct++)
        ob[(size_t)r * 64 + ct * 16 + lr] = f2bf(acc[rt][ct][e2]);
    }
  }
}

// out = relu(g*(agg-mu)*rsqrt(var+eps)+beta) + res   (conv bias cancels in BN)
__global__ __launch_bounds__(256) void k_bnrelu(
    const float* __restrict__ agg, const float* __restrict__ res,
    const float* __restrict__ stats, const float* __restrict__ g,
    const float* __restrict__ beta, float* __restrict__ out, int n) {
  int idx = blockIdx.x * 256 + threadIdx.x;
  if (idx >= n * 16) return;
  int c4 = (idx & 15) * 4;
  float invN = 1.0f / (float)n;
  float4 a = ((const float4*)agg)[idx];
  float4 rr = ((const float4*)res)[idx];
  float av[4] = {a.x, a.y, a.z, a.w};
  float rv[4] = {rr.x, rr.y, rr.z, rr.w};
  float vo[4];
#pragma unroll
  for (int j = 0; j < 4; j++) {
    int c = c4 + j;
    float mu = stats[c] * invN;
    float var = stats[64 + c] * invN - mu * mu;
    float sc = g[c] * rsqrtf(var + BN_EPS);
    float v = (av[j] - mu) * sc + beta[c];
    vo[j] = fmaxf(v, 0.0f) + rv[j];
  }
  ((float4*)out)[idx] = make_float4(vo[0], vo[1], vo[2], vo[3]);
}

extern "C" void kernel_launch(void* const* d_in, const int* in_sizes, int n_in,
                              void* d_out, int out_size, void* d_ws, size_t ws_size,
                              hipStream_t stream) {
  const float* x = (const float*)d_in[0];
  const int* ei = (const int*)d_in[1];
  const float* ew = (const float*)d_in[2];
  const float* W1 = (const float*)d_in[3];
  const float* g1 = (const float*)d_in[5];
  const float* be1 = (const float*)d_in[6];
  const float* W2 = (const float*)d_in[7];
  const float* g2 = (const float*)d_in[9];
  const float* be2 = (const float*)d_in[10];
  const float* pW = (const float*)d_in[11];
  const float* pb = (const float*)d_in[12];

  int n = in_sizes[0] / 128;
  int e = in_sizes[1] / 2;
  const int* row = ei;      // source
  const int* col = ei + e;  // target

  // workspace layout (spair padded by 32 int2)
  float* ws = (float*)d_ws;
  float* dis = ws;                             // n
  int* ptr = (int*)(dis + n);                  // n+4
  int* cnt = ptr + n + 4;                      // n
  int* rank = cnt + n;                         // e
  int* bsum = rank + e;                        // 1024
  int2* spair = (int2*)(bsum + 1024);          // e int2 (+32 pad)
  ushort* hwb = (ushort*)(spair + e + 32);     // n*64 bf16 (hw1, then hw2)
  float* bufR = (float*)(hwb + (size_t)n * 64);  // n*64 (residual)
  float* bufB = bufR + (size_t)n * 64;         // n*64 (agg)
  float* bufA = bufB + (size_t)n * 64;         // n*64 (h)
  float* stats = bufA + (size_t)n * 64;        // 128

  float* out = (float*)d_out;

  int nb_n = (n + 255) / 256;
  int nb_e = (e + 255) / 256;
  int nb_b = (n * 16 + 255) / 256;
  int nb_sc = (n + 1023) / 1024;
  int nb_g = (n + 127) / 128;

  // k_agg geometry: R14's verified best — 1024 blocks x 16 groups.
  constexpr int AGG_BLOCKS = 1024;
  int ngroups = AGG_BLOCKS * 16;
  int npg = (n + ngroups - 1) / ngroups;

  // CSR build + gcn_norm (gemm1 independent, placed between)
  hipMemsetAsync(cnt, 0, n * sizeof(int), stream);
  k_hist<<<nb_e, 256, 0, stream>>>(col, cnt, rank, e);
  k_gemm1m<<<nb_g, 256, 0, stream>>>(x, W1, pW, pb, hwb, bufR, n);
  k_scan_part<<<nb_sc, 256, 0, stream>>>(cnt, bsum, n);
  k_scan_mid<<<1, 1024, 0, stream>>>(bsum, nb_sc);
  k_scan_apply<<<nb_sc, 256, 0, stream>>>(cnt, ptr, bsum, n, e);
  k_fillcsr<<<nb_e, 256, 0, stream>>>(row, col, ew, ptr, rank, spair, e);
  k_degdis<<<nb_n, 256, 0, stream>>>(ptr, spair, dis, n);
  k_scale<<<nb_e, 256, 0, stream>>>(spair, dis, e);

  // layer 1 aggregation + stats
  hipMemsetAsync(stats, 0, 128 * sizeof(float), stream);
  k_agg<<<AGG_BLOCKS, 256, 0, stream>>>(ptr, spair, dis, hwb, bufB, stats, n, npg);

  // layer 2: fused bn1/relu/residual + gemm2 (writes h -> bufA, hw2 -> hwb)
  k_gemm2bn<<<nb_g, 256, 0, stream>>>(bufB, bufR, stats, g1, be1, W2, bufA, hwb, n);
  hipMemsetAsync(stats, 0, 128 * sizeof(float), stream);
  k_agg<<<AGG_BLOCKS, 256, 0, stream>>>(ptr, spair, dis, hwb, bufB, stats, n, npg);
  k_bnrelu<<<nb_b, 256, 0, stream>>>(bufB, bufA, stats, g2, be2, out, n);
}